// Round 1
// baseline (951.266 us; speedup 1.0000x reference)
//
#include <hip/hip_runtime.h>
#include <math.h>

// ---------------------------------------------------------------------------
// Problem: S=8192 persons, F=1024 features, A=256 attn len (derived at launch)
// out = ( w_norm @ relu(batch@W_g+b_g) [S,A],  tanh(batch@W_h+b_h) [S,2] )
// w_ij = valid_i&valid_j ? 1/(dist_ij+1e-4) : 0, row-normalized.
// Single pass: accumulate unnormalized + rowsum, scale at end.
// ---------------------------------------------------------------------------

// Kernel 1: hp = tanh(batch@W_h + b_h); hx,hy,validf per row. One wave per row.
__global__ __launch_bounds__(256) void k_head(
    const float* __restrict__ batch, const float* __restrict__ xywh,
    const float* __restrict__ W_h, const float* __restrict__ b_h,
    float* __restrict__ hp_out, float* __restrict__ hx, float* __restrict__ hy,
    float* __restrict__ validf, int S, int F) {
  int wid = threadIdx.x >> 6;
  int lane = threadIdx.x & 63;
  int row = blockIdx.x * 4 + wid;
  if (row >= S) return;
  const float4* brow = (const float4*)(batch + (size_t)row * F);
  const float4* wh4 = (const float4*)W_h;  // W_h is [F,2] row-major
  int nf4 = F >> 2;
  float acc0 = 0.f, acc1 = 0.f;
  for (int k4 = lane; k4 < nf4; k4 += 64) {
    float4 b = brow[k4];
    float4 wa = wh4[2 * k4];      // (k,0)(k,1)(k+1,0)(k+1,1)
    float4 wb = wh4[2 * k4 + 1];  // (k+2,0)(k+2,1)(k+3,0)(k+3,1)
    acc0 += b.x * wa.x + b.y * wa.z + b.z * wb.x + b.w * wb.z;
    acc1 += b.x * wa.y + b.y * wa.w + b.z * wb.y + b.w * wb.w;
  }
  #pragma unroll
  for (int off = 32; off; off >>= 1) {
    acc0 += __shfl_xor(acc0, off, 64);
    acc1 += __shfl_xor(acc1, off, 64);
  }
  if (lane == 0) {
    float hp0 = tanhf(acc0 + b_h[0]);
    float hp1 = tanhf(acc1 + b_h[1]);
    float4 xy = ((const float4*)xywh)[row];
    hp_out[2 * row] = hp0;
    hp_out[2 * row + 1] = hp1;
    hx[row] = hp0 * xy.z * 4.0f + xy.x;  // SIGMA_X = 4
    hy[row] = hp1 * xy.w * 1.0f + xy.y;  // SIGMA_Y = 1
    validf[row] = (xy.x + xy.y + xy.z + xy.w >= 1e-8f) ? 1.0f : 0.0f;
  }
}

// Kernel 2: targets = relu(batch @ W_g + b_g).  64x64 block tile, 4x4/thread,
// register-only (W_g is L2-resident at 1 MB; batch rows broadcast via L1).
__global__ __launch_bounds__(256) void k_targets(
    const float* __restrict__ batch, const float* __restrict__ Wg,
    const float* __restrict__ bg, float* __restrict__ targets,
    int S, int F, int A) {
  int t = threadIdx.x;
  int tx = t & 15, ty = t >> 4;
  int i0 = blockIdx.y * 64;
  int a0 = blockIdx.x * 64;
  int aa = a0 + tx * 4;
  float acc[4][4] = {};
  #pragma unroll 2
  for (int k0 = 0; k0 < F; k0 += 4) {
    float4 bv[4], wv[4];
    #pragma unroll
    for (int r = 0; r < 4; ++r)
      bv[r] = *(const float4*)(batch + (size_t)(i0 + ty * 4 + r) * F + k0);
    #pragma unroll
    for (int e = 0; e < 4; ++e)
      wv[e] = *(const float4*)(Wg + (size_t)(k0 + e) * A + aa);
    #pragma unroll
    for (int r = 0; r < 4; ++r) {
      acc[r][0] += bv[r].x*wv[0].x + bv[r].y*wv[1].x + bv[r].z*wv[2].x + bv[r].w*wv[3].x;
      acc[r][1] += bv[r].x*wv[0].y + bv[r].y*wv[1].y + bv[r].z*wv[2].y + bv[r].w*wv[3].y;
      acc[r][2] += bv[r].x*wv[0].z + bv[r].y*wv[1].z + bv[r].z*wv[2].z + bv[r].w*wv[3].z;
      acc[r][3] += bv[r].x*wv[0].w + bv[r].y*wv[1].w + bv[r].z*wv[2].w + bv[r].w*wv[3].w;
    }
  }
  float4 bgv = *(const float4*)(bg + aa);
  #pragma unroll
  for (int r = 0; r < 4; ++r) {
    float4 o;
    o.x = fmaxf(acc[r][0] + bgv.x, 0.f);
    o.y = fmaxf(acc[r][1] + bgv.y, 0.f);
    o.z = fmaxf(acc[r][2] + bgv.z, 0.f);
    o.w = fmaxf(acc[r][3] + bgv.w, 0.f);
    *(float4*)(targets + (size_t)(i0 + ty * 4 + r) * A + aa) = o;
  }
}

// Kernel 3: out = rownorm(W) @ targets, W computed on the fly.
// 64(i) x 64(a) block tile, 4x4/thread, KJ=32. Rowsum folded in.
__global__ __launch_bounds__(256) void k_gather(
    const float* __restrict__ targets, const float* __restrict__ xywh,
    const float* __restrict__ hx, const float* __restrict__ hy,
    const float* __restrict__ validf, float* __restrict__ out, int S, int A) {
  __shared__ float hxs[64], hys[64], vls[64], scale_s[64];
  __shared__ float wT[32][64];  // w[jj][ii]
  __shared__ float ts[32][64];  // targets[jj][aa]
  int t = threadIdx.x;
  int tx = t & 15, ty = t >> 4;
  int i0 = blockIdx.y * 64, a0 = blockIdx.x * 64;
  if (t < 64) {
    hxs[t] = hx[i0 + t];
    hys[t] = hy[i0 + t];
    vls[t] = validf[i0 + t];
  }
  __syncthreads();
  float acc[4][4] = {};
  float rs_part[8] = {};
  int wjj = t >> 3;         // 0..31  (j within tile, fixed per thread)
  int wi0 = (t & 7) * 8;    // 0..56  (8 consecutive i's per thread)

  for (int j0 = 0; j0 < S; j0 += 32) {
    // issue global loads early (targets tile slice + this thread's xywh row)
    const float* trow = targets + (size_t)(j0 + wjj) * A + a0 + wi0;
    float4 ta = *(const float4*)(trow);
    float4 tb = *(const float4*)(trow + 4);
    float4 xj = *(const float4*)(xywh + (size_t)(j0 + wjj) * 4);
    float vj = (xj.x + xj.y + xj.z + xj.w >= 1e-8f) ? 1.0f : 0.0f;
    float wv[8];
    #pragma unroll
    for (int e = 0; e < 8; ++e) {
      float dx = hxs[wi0 + e] - xj.x;
      float dy = hys[wi0 + e] - xj.y;
      float dis = sqrtf(dx * dx + dy * dy);
      float w = vj / (dis + 1e-4f);
      rs_part[e] += w;
      wv[e] = w;
    }
    __syncthreads();  // prior tile's LDS reads complete
    *(float4*)&wT[wjj][wi0]     = make_float4(wv[0], wv[1], wv[2], wv[3]);
    *(float4*)&wT[wjj][wi0 + 4] = make_float4(wv[4], wv[5], wv[6], wv[7]);
    *(float4*)&ts[wjj][wi0]     = ta;
    *(float4*)&ts[wjj][wi0 + 4] = tb;
    __syncthreads();
    #pragma unroll 4
    for (int jj = 0; jj < 32; ++jj) {
      float4 w4 = *(const float4*)&wT[jj][ty * 4];
      float4 t4 = *(const float4*)&ts[jj][tx * 4];
      acc[0][0] += w4.x*t4.x; acc[0][1] += w4.x*t4.y; acc[0][2] += w4.x*t4.z; acc[0][3] += w4.x*t4.w;
      acc[1][0] += w4.y*t4.x; acc[1][1] += w4.y*t4.y; acc[1][2] += w4.y*t4.z; acc[1][3] += w4.y*t4.w;
      acc[2][0] += w4.z*t4.x; acc[2][1] += w4.z*t4.y; acc[2][2] += w4.z*t4.z; acc[2][3] += w4.z*t4.w;
      acc[3][0] += w4.w*t4.x; acc[3][1] += w4.w*t4.y; acc[3][2] += w4.w*t4.z; acc[3][3] += w4.w*t4.w;
    }
  }

  // reduce rowsum partials: wT reused as [jj][ii] partial store
  __syncthreads();
  #pragma unroll
  for (int e = 0; e < 8; ++e) wT[wjj][wi0 + e] = rs_part[e];
  __syncthreads();
  if (t < 64) {
    float rs = 0.f;
    #pragma unroll 8
    for (int jj = 0; jj < 32; ++jj) rs += wT[jj][t];
    scale_s[t] = (vls[t] > 0.f) ? 1.0f / fmaxf(rs, 1e-30f) : 0.0f;
  }
  __syncthreads();
  #pragma unroll
  for (int r = 0; r < 4; ++r) {
    float s = scale_s[ty * 4 + r];
    float4 o = make_float4(acc[r][0] * s, acc[r][1] * s, acc[r][2] * s, acc[r][3] * s);
    *(float4*)(out + (size_t)(i0 + ty * 4 + r) * A + a0 + tx * 4) = o;
  }
}

extern "C" void kernel_launch(void* const* d_in, const int* in_sizes, int n_in,
                              void* d_out, int out_size, void* d_ws, size_t ws_size,
                              hipStream_t stream) {
  // setup_inputs order:
  // 0 batch_data[S,F] 1 xywh[S,4] 2 OW 3 OH 4 actor_weights[S] 5 avg_pos[S,2]
  // 6 W_h[F,2] 7 b_h[2] 8 W_g[F,A] 9 b_g[A] 10 num_person
  const float* batch = (const float*)d_in[0];
  const float* xywh  = (const float*)d_in[1];
  const float* W_h   = (const float*)d_in[6];
  const float* b_h   = (const float*)d_in[7];
  const float* W_g   = (const float*)d_in[8];
  const float* b_g   = (const float*)d_in[9];
  int S = in_sizes[4];            // actor_weights is [S]
  int F = in_sizes[0] / S;
  int A = in_sizes[9];            // b_g is [A]

  float* out    = (float*)d_out;
  float* out_tw = out;                       // [S,A]
  float* out_hp = out + (size_t)S * A;       // [S,2]

  float* ws      = (float*)d_ws;
  float* targets = ws;                       // [S,A] fp32
  float* hxv     = targets + (size_t)S * A;  // [S]
  float* hyv     = hxv + S;                  // [S]
  float* vfv     = hyv + S;                  // [S]

  k_head<<<dim3((S + 3) / 4), 256, 0, stream>>>(batch, xywh, W_h, b_h,
                                                out_hp, hxv, hyv, vfv, S, F);
  k_targets<<<dim3(A / 64, S / 64), 256, 0, stream>>>(batch, W_g, b_g,
                                                      targets, S, F, A);
  k_gather<<<dim3(A / 64, S / 64), 256, 0, stream>>>(targets, xywh, hxv, hyv,
                                                     vfv, out_tw, S, A);
}

// Round 2
// 431.479 us; speedup vs baseline: 2.2047x; 2.2047x over previous
//
#include <hip/hip_runtime.h>
#include <math.h>
#include <stdint.h>

typedef __attribute__((ext_vector_type(8))) short short8;
typedef __attribute__((ext_vector_type(4))) float f32x4;

__device__ __forceinline__ uint32_t bf_rne(float f) {
  uint32_t u = __float_as_uint(f);
  return (u + 0x7fffu + ((u >> 16) & 1u)) >> 16;
}

// ---------------------------------------------------------------------------
// Kernel 1: hp = tanh(batch@W_h + b_h); hx,hy,validf per row. One wave per row.
__global__ __launch_bounds__(256) void k_head(
    const float* __restrict__ batch, const float* __restrict__ xywh,
    const float* __restrict__ W_h, const float* __restrict__ b_h,
    float* __restrict__ hp_out, float* __restrict__ hx, float* __restrict__ hy,
    float* __restrict__ validf, int S, int F) {
  int wid = threadIdx.x >> 6;
  int lane = threadIdx.x & 63;
  int row = blockIdx.x * 4 + wid;
  if (row >= S) return;
  const float4* brow = (const float4*)(batch + (size_t)row * F);
  const float4* wh4 = (const float4*)W_h;  // W_h is [F,2] row-major
  int nf4 = F >> 2;
  float acc0 = 0.f, acc1 = 0.f;
  for (int k4 = lane; k4 < nf4; k4 += 64) {
    float4 b = brow[k4];
    float4 wa = wh4[2 * k4];
    float4 wb = wh4[2 * k4 + 1];
    acc0 += b.x * wa.x + b.y * wa.z + b.z * wb.x + b.w * wb.z;
    acc1 += b.x * wa.y + b.y * wa.w + b.z * wb.y + b.w * wb.w;
  }
  #pragma unroll
  for (int off = 32; off; off >>= 1) {
    acc0 += __shfl_xor(acc0, off, 64);
    acc1 += __shfl_xor(acc1, off, 64);
  }
  if (lane == 0) {
    float hp0 = tanhf(acc0 + b_h[0]);
    float hp1 = tanhf(acc1 + b_h[1]);
    float4 xy = ((const float4*)xywh)[row];
    hp_out[2 * row] = hp0;
    hp_out[2 * row + 1] = hp1;
    hx[row] = hp0 * xy.z * 4.0f + xy.x;  // SIGMA_X = 4
    hy[row] = hp1 * xy.w * 1.0f + xy.y;  // SIGMA_Y = 1
    validf[row] = (xy.x + xy.y + xy.z + xy.w >= 1e-8f) ? 1.0f : 0.0f;
  }
}

// ---------------------------------------------------------------------------
// Kernel 2: targets = relu(batch @ W_g + b_g), written TRANSPOSED as bf16:
// tgtT[a][i]  (A x S). fp32 accumulate (accuracy), bf16 only at the write.
__global__ __launch_bounds__(256) void k_targets_t(
    const float* __restrict__ batch, const float* __restrict__ Wg,
    const float* __restrict__ bg, uint16_t* __restrict__ tgtT,
    int S, int F, int A) {
  int t = threadIdx.x;
  int tx = t & 15, ty = t >> 4;
  int i0 = blockIdx.y * 64;
  int a0 = blockIdx.x * 64;
  int aa = a0 + tx * 4;
  float acc[4][4] = {};
  #pragma unroll 2
  for (int k0 = 0; k0 < F; k0 += 4) {
    float4 bv[4], wv[4];
    #pragma unroll
    for (int r = 0; r < 4; ++r)
      bv[r] = *(const float4*)(batch + (size_t)(i0 + ty * 4 + r) * F + k0);
    #pragma unroll
    for (int e = 0; e < 4; ++e)
      wv[e] = *(const float4*)(Wg + (size_t)(k0 + e) * A + aa);
    #pragma unroll
    for (int r = 0; r < 4; ++r) {
      acc[r][0] += bv[r].x*wv[0].x + bv[r].y*wv[1].x + bv[r].z*wv[2].x + bv[r].w*wv[3].x;
      acc[r][1] += bv[r].x*wv[0].y + bv[r].y*wv[1].y + bv[r].z*wv[2].y + bv[r].w*wv[3].y;
      acc[r][2] += bv[r].x*wv[0].z + bv[r].y*wv[1].z + bv[r].z*wv[2].z + bv[r].w*wv[3].z;
      acc[r][3] += bv[r].x*wv[0].w + bv[r].y*wv[1].w + bv[r].z*wv[2].w + bv[r].w*wv[3].w;
    }
  }
  float4 bgv = *(const float4*)(bg + aa);
  float bgc[4] = {bgv.x, bgv.y, bgv.z, bgv.w};
  #pragma unroll
  for (int c = 0; c < 4; ++c) {
    float o0 = fmaxf(acc[0][c] + bgc[c], 0.f);
    float o1 = fmaxf(acc[1][c] + bgc[c], 0.f);
    float o2 = fmaxf(acc[2][c] + bgc[c], 0.f);
    float o3 = fmaxf(acc[3][c] + bgc[c], 0.f);
    uint2 pk;
    pk.x = bf_rne(o0) | (bf_rne(o1) << 16);
    pk.y = bf_rne(o2) | (bf_rne(o3) << 16);
    // rows r are consecutive i -> 8B contiguous store at tgtT[a][i0+ty*4]
    *(uint2*)(tgtT + (size_t)(aa + c) * S + i0 + ty * 4) = pk;
  }
}

// ---------------------------------------------------------------------------
// Kernel 3: out = rownorm(W) @ targets via bf16 MFMA, W computed on the fly.
// Grid: S/32 blocks, 512 threads (8 waves: 2(M) x 4(N)). BM=32, BN=A=256.
// Per K-step (32 j's): compute w tile fp32 -> bf16 -> LDS (padded 80B rows,
// double-buffered); B-frags read direct from tgtT (k-contiguous); 4 MFMA/wave.
__global__ __launch_bounds__(512) void k_gather_mfma(
    const uint16_t* __restrict__ tgtT, const float* __restrict__ xywh,
    const float* __restrict__ hx, const float* __restrict__ hy,
    const float* __restrict__ validf, float* __restrict__ out, int S, int A) {
  __shared__ uint32_t wlds[2][32 * 20];   // [i][20 u32] = 80B padded rows
  __shared__ float rs_lds[32][17];
  __shared__ float scale_s[32];

  int t = threadIdx.x;
  int lane = t & 63, wid = t >> 6;
  int wm = wid >> 2, wn = wid & 3;        // wave grid 2(M) x 4(N)
  int i0 = blockIdx.x * 32;

  // w-generation assignment: fixed (i, j-pair) per thread
  int gi = t & 31;
  int gjh = t >> 5;                        // 0..15 -> j pair = 2*gjh
  float hx_i = hx[i0 + gi];
  float hy_i = hy[i0 + gi];
  float rs = 0.f;

  // MFMA per-lane constants
  int m_loc = wm * 16 + (lane & 15);
  int kch = lane >> 4;                     // k-chunk 0..3 (8 k's each)
  const uint32_t* a_ptr[2] = {
      &wlds[0][m_loc * 20 + kch * 4],
      &wlds[1][m_loc * 20 + kch * 4]};
  int n0 = wn * 64 + (lane & 15);          // global a for B frags (+nf*16)

  f32x4 acc[4] = {};

  int nsteps = S / 32;
  for (int ts = 0; ts < nsteps; ++ts) {
    int j0 = ts * 32;
    // --- issue B loads early (consumed by MFMA after the barrier) ---
    short8 bfr[4];
    const uint16_t* bp = tgtT + (size_t)n0 * S + j0 + kch * 8;
    #pragma unroll
    for (int nf = 0; nf < 4; ++nf)
      bfr[nf] = *(const short8*)(bp + (size_t)(nf * 16) * S);

    // --- w tile generation (2 values per thread) ---
    int j = j0 + 2 * gjh;
    float4 xa = *(const float4*)(xywh + 4 * j);
    float4 xb = *(const float4*)(xywh + 4 * (j + 1));
    float va = (xa.x + xa.y + xa.z + xa.w >= 1e-8f) ? 1.f : 0.f;
    float vb = (xb.x + xb.y + xb.z + xb.w >= 1e-8f) ? 1.f : 0.f;
    float dx0 = hx_i - xa.x, dy0 = hy_i - xa.y;
    float dx1 = hx_i - xb.x, dy1 = hy_i - xb.y;
    float d0 = __builtin_amdgcn_sqrtf(dx0 * dx0 + dy0 * dy0);
    float d1 = __builtin_amdgcn_sqrtf(dx1 * dx1 + dy1 * dy1);
    float w0 = va * __builtin_amdgcn_rcpf(d0 + 1e-4f);
    float w1 = vb * __builtin_amdgcn_rcpf(d1 + 1e-4f);
    uint32_t q0 = bf_rne(w0), q1 = bf_rne(w1);
    // rowsum over the bf16-ROUNDED weights (numerator/denominator cancel)
    rs += __uint_as_float(q0 << 16) + __uint_as_float(q1 << 16);
    wlds[ts & 1][gi * 20 + gjh] = q0 | (q1 << 16);

    __syncthreads();  // w tile visible; dbuf means no trailing barrier needed

    short8 afr = *(const short8*)a_ptr[ts & 1];
    #pragma unroll
    for (int nf = 0; nf < 4; ++nf)
      acc[nf] = __builtin_amdgcn_mfma_f32_16x16x32_bf16(afr, bfr[nf], acc[nf], 0, 0, 0);
  }

  // --- rowsum reduction + scale ---
  __syncthreads();
  rs_lds[gi][gjh] = rs;
  __syncthreads();
  if (t < 32) {
    float r = 0.f;
    #pragma unroll
    for (int g = 0; g < 16; ++g) r += rs_lds[t][g];
    float v = validf[i0 + t];
    scale_s[t] = (v > 0.f) ? 1.0f / fmaxf(r, 1e-30f) : 0.f;
  }
  __syncthreads();

  // --- epilogue: scale + store (C/D: col=lane&15, row=(lane>>4)*4+r) ---
  int mrow = wm * 16 + (lane >> 4) * 4;
  #pragma unroll
  for (int r = 0; r < 4; ++r) {
    float s = scale_s[mrow + r];
    size_t base = (size_t)(i0 + mrow + r) * A + wn * 64 + (lane & 15);
    #pragma unroll
    for (int nf = 0; nf < 4; ++nf)
      out[base + nf * 16] = acc[nf][r] * s;
  }
}

extern "C" void kernel_launch(void* const* d_in, const int* in_sizes, int n_in,
                              void* d_out, int out_size, void* d_ws, size_t ws_size,
                              hipStream_t stream) {
  // inputs: 0 batch[S,F] 1 xywh[S,4] 2 OW 3 OH 4 actor_weights[S] 5 avg_pos[S,2]
  //         6 W_h[F,2] 7 b_h[2] 8 W_g[F,A] 9 b_g[A] 10 num_person
  const float* batch = (const float*)d_in[0];
  const float* xywh  = (const float*)d_in[1];
  const float* W_h   = (const float*)d_in[6];
  const float* b_h   = (const float*)d_in[7];
  const float* W_g   = (const float*)d_in[8];
  const float* b_g   = (const float*)d_in[9];
  int S = in_sizes[4];
  int F = in_sizes[0] / S;
  int A = in_sizes[9];

  float* out    = (float*)d_out;
  float* out_tw = out;                        // [S,A]
  float* out_hp = out + (size_t)S * A;        // [S,2]

  // workspace: tgtT bf16 [A][S] + hx/hy/validf [S]
  uint16_t* tgtT = (uint16_t*)d_ws;
  float* hxv = (float*)(tgtT + (size_t)A * S);
  float* hyv = hxv + S;
  float* vfv = hyv + S;

  k_head<<<dim3((S + 3) / 4), 256, 0, stream>>>(batch, xywh, W_h, b_h,
                                                out_hp, hxv, hyv, vfv, S, F);
  k_targets_t<<<dim3(A / 64, S / 64), 256, 0, stream>>>(batch, W_g, b_g,
                                                        tgtT, S, F, A);
  k_gather_mfma<<<dim3(S / 32), 512, 0, stream>>>(tgtT, xywh, hxv, hyv,
                                                  vfv, out_tw, S, A);
}

// Round 3
// 334.362 us; speedup vs baseline: 2.8450x; 1.2905x over previous
//
#include <hip/hip_runtime.h>
#include <math.h>
#include <stdint.h>

typedef __attribute__((ext_vector_type(8))) short short8;
typedef __attribute__((ext_vector_type(4))) float f32x4;

__device__ __forceinline__ uint32_t cvt_pk_bf16(float lo, float hi) {
  uint32_t r;
  asm("v_cvt_pk_bf16_f32 %0, %1, %2" : "=v"(r) : "v"(lo), "v"(hi));
  return r;
}

// inverse-distance weight; invalid j has cx=cy=1e30 -> d2 overflows to inf
// -> rcp(inf)=0, so invalid columns contribute exactly 0.
__device__ __forceinline__ float wfun(float hx, float hy, float cx, float cy) {
  float dx = hx - cx, dy = hy - cy;
  float d = __builtin_amdgcn_sqrtf(fmaf(dx, dx, dy * dy));
  return __builtin_amdgcn_rcpf(d + 1e-4f);
}

// ---------------------------------------------------------------------------
// Kernel 1: hp = tanh(batch@W_h + b_h); hx,hy,validf,cxy per row.
__global__ __launch_bounds__(256) void k_head(
    const float* __restrict__ batch, const float* __restrict__ xywh,
    const float* __restrict__ W_h, const float* __restrict__ b_h,
    float* __restrict__ hp_out, float* __restrict__ hx, float* __restrict__ hy,
    float* __restrict__ validf, float2* __restrict__ cxy, int S, int F) {
  int wid = threadIdx.x >> 6;
  int lane = threadIdx.x & 63;
  int row = blockIdx.x * 4 + wid;
  if (row >= S) return;
  const float4* brow = (const float4*)(batch + (size_t)row * F);
  const float4* wh4 = (const float4*)W_h;  // W_h is [F,2] row-major
  int nf4 = F >> 2;
  float acc0 = 0.f, acc1 = 0.f;
  for (int k4 = lane; k4 < nf4; k4 += 64) {
    float4 b = brow[k4];
    float4 wa = wh4[2 * k4];
    float4 wb = wh4[2 * k4 + 1];
    acc0 += b.x * wa.x + b.y * wa.z + b.z * wb.x + b.w * wb.z;
    acc1 += b.x * wa.y + b.y * wa.w + b.z * wb.y + b.w * wb.w;
  }
  #pragma unroll
  for (int off = 32; off; off >>= 1) {
    acc0 += __shfl_xor(acc0, off, 64);
    acc1 += __shfl_xor(acc1, off, 64);
  }
  if (lane == 0) {
    float hp0 = tanhf(acc0 + b_h[0]);
    float hp1 = tanhf(acc1 + b_h[1]);
    float4 xy = ((const float4*)xywh)[row];
    hp_out[2 * row] = hp0;
    hp_out[2 * row + 1] = hp1;
    hx[row] = hp0 * xy.z * 4.0f + xy.x;  // SIGMA_X = 4
    hy[row] = hp1 * xy.w * 1.0f + xy.y;  // SIGMA_Y = 1
    bool v = (xy.x + xy.y + xy.z + xy.w >= 1e-8f);
    validf[row] = v ? 1.0f : 0.0f;
    cxy[row] = v ? make_float2(xy.x, xy.y) : make_float2(1e30f, 1e30f);
  }
}

// ---------------------------------------------------------------------------
// Kernel 1b: WgT[a][k] = bf16(Wg[k][a])  (A x F, transposed for B-frags)
__global__ __launch_bounds__(256) void k_prep_w(
    const float* __restrict__ Wg, uint16_t* __restrict__ WgT, int F, int A) {
  int idx = blockIdx.x * 256 + threadIdx.x;  // A*F/8 threads
  int a = idx % A;
  int k0 = (idx / A) * 8;
  if (k0 >= F) return;
  float f[8];
  #pragma unroll
  for (int e = 0; e < 8; ++e) f[e] = Wg[(size_t)(k0 + e) * A + a];
  uint4 v;
  v.x = cvt_pk_bf16(f[0], f[1]);
  v.y = cvt_pk_bf16(f[2], f[3]);
  v.z = cvt_pk_bf16(f[4], f[5]);
  v.w = cvt_pk_bf16(f[6], f[7]);
  *(uint4*)(WgT + (size_t)a * F + k0) = v;
}

// ---------------------------------------------------------------------------
// Kernel 2: tgtT[a][i] = bf16(relu(batch @ Wg + bg))  via bf16 MFMA.
// Block 256 thr = 4 waves (2M x 2N). BM=32, per-wave N=128 (8 frags).
// Barrier-free; A cast fp32->bf16 in-register; 1-step register prefetch.
__global__ __launch_bounds__(256) void k_targets_mfma(
    const float* __restrict__ batch, const uint16_t* __restrict__ WgT,
    const float* __restrict__ bg, uint16_t* __restrict__ tgtT,
    int S, int F, int A) {
  int t = threadIdx.x;
  int lane = t & 63, wid = t >> 6;
  int wm = wid >> 1, wn = wid & 1;
  int i0 = blockIdx.x * 32;
  int row = i0 + wm * 16 + (lane & 15);
  int kch = lane >> 4;
  const float* ab = batch + (size_t)row * F + kch * 8;
  int ncol0 = wn * 128 + (lane & 15);
  const uint16_t* bb = WgT + (size_t)ncol0 * F + kch * 8;

  f32x4 acc[8] = {};
  float4 a0 = *(const float4*)(ab);
  float4 a1 = *(const float4*)(ab + 4);
  short8 bf[8];
  #pragma unroll
  for (int nf = 0; nf < 8; ++nf)
    bf[nf] = *(const short8*)(bb + (size_t)nf * 16 * F);

  for (int k0 = 0; k0 < F; k0 += 32) {
    int kn = (k0 + 32 < F) ? k0 + 32 : 0;  // wrap prefetch (harmless)
    float4 na0 = *(const float4*)(ab + kn);
    float4 na1 = *(const float4*)(ab + kn + 4);
    short8 nbf[8];
    #pragma unroll
    for (int nf = 0; nf < 8; ++nf)
      nbf[nf] = *(const short8*)(bb + kn + (size_t)nf * 16 * F);
    union { short8 s; uint32_t u[4]; } af;
    af.u[0] = cvt_pk_bf16(a0.x, a0.y);
    af.u[1] = cvt_pk_bf16(a0.z, a0.w);
    af.u[2] = cvt_pk_bf16(a1.x, a1.y);
    af.u[3] = cvt_pk_bf16(a1.z, a1.w);
    #pragma unroll
    for (int nf = 0; nf < 8; ++nf)
      acc[nf] = __builtin_amdgcn_mfma_f32_16x16x32_bf16(af.s, bf[nf], acc[nf], 0, 0, 0);
    a0 = na0; a1 = na1;
    #pragma unroll
    for (int nf = 0; nf < 8; ++nf) bf[nf] = nbf[nf];
  }

  int rbase = i0 + wm * 16 + (lane >> 4) * 4;
  #pragma unroll
  for (int nf = 0; nf < 8; ++nf) {
    int col = ncol0 + nf * 16;
    float b = bg[col];
    float o0 = fmaxf(acc[nf][0] + b, 0.f);
    float o1 = fmaxf(acc[nf][1] + b, 0.f);
    float o2 = fmaxf(acc[nf][2] + b, 0.f);
    float o3 = fmaxf(acc[nf][3] + b, 0.f);
    uint2 pk;
    pk.x = cvt_pk_bf16(o0, o1);
    pk.y = cvt_pk_bf16(o2, o3);
    *(uint2*)(tgtT + (size_t)col * S + rbase) = pk;
  }
}

// ---------------------------------------------------------------------------
// Kernel 3: out = rownorm(W) @ targets. BARRIER-FREE: each lane computes its
// own A-fragment w values directly (A layout: row=lane&15, k=(lane>>4)*8+e).
// Block 512 thr = 8 waves (2M x 4N), BM=32, grid=S/32=256. B-frags + cxy
// prefetched 1 step ahead in registers. Rowsum per-lane fp32 + shfl reduce.
__global__ __launch_bounds__(512) void k_gather_v3(
    const uint16_t* __restrict__ tgtT, const float2* __restrict__ cxy,
    const float* __restrict__ hx, const float* __restrict__ hy,
    const float* __restrict__ validf, float* __restrict__ out, int S, int A) {
  __shared__ float scale_s[32];
  int t = threadIdx.x;
  int lane = t & 63, wid = t >> 6;
  int wm = wid >> 2, wn = wid & 3;  // 2M x 4N
  int i0 = blockIdx.x * 32;
  int mrow = i0 + wm * 16 + (lane & 15);
  int kch = lane >> 4;
  float hx_i = hx[mrow], hy_i = hy[mrow];
  int n0 = wn * 64 + (lane & 15);
  const uint16_t* bbase = tgtT + (size_t)n0 * S + kch * 8;
  const float2* cbase = cxy + kch * 8;

  f32x4 acc[4] = {};
  float rs = 0.f;

  // prefetch step 0
  float4 c0 = *(const float4*)(cbase);
  float4 c1 = *(const float4*)(cbase + 2);
  float4 c2 = *(const float4*)(cbase + 4);
  float4 c3 = *(const float4*)(cbase + 6);
  short8 b0 = *(const short8*)(bbase);
  short8 b1 = *(const short8*)(bbase + (size_t)16 * S);
  short8 b2 = *(const short8*)(bbase + (size_t)32 * S);
  short8 b3 = *(const short8*)(bbase + (size_t)48 * S);

  int nsteps = S / 32;
  for (int ts = 0; ts < nsteps; ++ts) {
    int jn = (ts + 1 < nsteps) ? (ts + 1) * 32 : 0;  // wrap prefetch
    const float4* cpn = (const float4*)(cbase + jn);
    float4 nc0 = cpn[0];
    float4 nc1 = cpn[1];
    float4 nc2 = cpn[2];
    float4 nc3 = cpn[3];
    const uint16_t* bpn = bbase + jn;
    short8 nb0 = *(const short8*)(bpn);
    short8 nb1 = *(const short8*)(bpn + (size_t)16 * S);
    short8 nb2 = *(const short8*)(bpn + (size_t)32 * S);
    short8 nb3 = *(const short8*)(bpn + (size_t)48 * S);

    // 8 w's for this lane's A fragment
    float w0 = wfun(hx_i, hy_i, c0.x, c0.y);
    float w1 = wfun(hx_i, hy_i, c0.z, c0.w);
    float w2 = wfun(hx_i, hy_i, c1.x, c1.y);
    float w3 = wfun(hx_i, hy_i, c1.z, c1.w);
    float w4 = wfun(hx_i, hy_i, c2.x, c2.y);
    float w5 = wfun(hx_i, hy_i, c2.z, c2.w);
    float w6 = wfun(hx_i, hy_i, c3.x, c3.y);
    float w7 = wfun(hx_i, hy_i, c3.z, c3.w);
    rs += ((w0 + w1) + (w2 + w3)) + ((w4 + w5) + (w6 + w7));
    union { short8 s; uint32_t u[4]; } af;
    af.u[0] = cvt_pk_bf16(w0, w1);
    af.u[1] = cvt_pk_bf16(w2, w3);
    af.u[2] = cvt_pk_bf16(w4, w5);
    af.u[3] = cvt_pk_bf16(w6, w7);

    acc[0] = __builtin_amdgcn_mfma_f32_16x16x32_bf16(af.s, b0, acc[0], 0, 0, 0);
    acc[1] = __builtin_amdgcn_mfma_f32_16x16x32_bf16(af.s, b1, acc[1], 0, 0, 0);
    acc[2] = __builtin_amdgcn_mfma_f32_16x16x32_bf16(af.s, b2, acc[2], 0, 0, 0);
    acc[3] = __builtin_amdgcn_mfma_f32_16x16x32_bf16(af.s, b3, acc[3], 0, 0, 0);

    c0 = nc0; c1 = nc1; c2 = nc2; c3 = nc3;
    b0 = nb0; b1 = nb1; b2 = nb2; b3 = nb3;
  }

  // full row sum: combine the 4 kch groups (wn waves hold identical sums)
  rs += __shfl_xor(rs, 16, 64);
  rs += __shfl_xor(rs, 32, 64);
  if (wn == 0 && lane < 16) {
    float v = validf[i0 + wm * 16 + lane];
    scale_s[wm * 16 + lane] = (v > 0.f) ? 1.0f / fmaxf(rs, 1e-30f) : 0.f;
  }
  __syncthreads();

  int mre = wm * 16 + (lane >> 4) * 4;
  #pragma unroll
  for (int r = 0; r < 4; ++r) {
    float s = scale_s[mre + r];
    size_t base = (size_t)(i0 + mre + r) * A + wn * 64 + (lane & 15);
    out[base]      = acc[0][r] * s;
    out[base + 16] = acc[1][r] * s;
    out[base + 32] = acc[2][r] * s;
    out[base + 48] = acc[3][r] * s;
  }
}

extern "C" void kernel_launch(void* const* d_in, const int* in_sizes, int n_in,
                              void* d_out, int out_size, void* d_ws, size_t ws_size,
                              hipStream_t stream) {
  // inputs: 0 batch[S,F] 1 xywh[S,4] 2 OW 3 OH 4 actor_weights[S] 5 avg_pos[S,2]
  //         6 W_h[F,2] 7 b_h[2] 8 W_g[F,A] 9 b_g[A] 10 num_person
  const float* batch = (const float*)d_in[0];
  const float* xywh  = (const float*)d_in[1];
  const float* W_h   = (const float*)d_in[6];
  const float* b_h   = (const float*)d_in[7];
  const float* W_g   = (const float*)d_in[8];
  const float* b_g   = (const float*)d_in[9];
  int S = in_sizes[4];
  int F = in_sizes[0] / S;
  int A = in_sizes[9];

  float* out    = (float*)d_out;
  float* out_tw = out;                        // [S,A]
  float* out_hp = out + (size_t)S * A;        // [S,2]

  // workspace: tgtT bf16 [A][S], WgT bf16 [A][F], hx/hy/validf [S], cxy [S,2]
  uint16_t* tgtT = (uint16_t*)d_ws;
  uint16_t* WgT  = tgtT + (size_t)A * S;
  float* hxv = (float*)(WgT + (size_t)A * F);
  float* hyv = hxv + S;
  float* vfv = hyv + S;
  float2* cxyv = (float2*)(vfv + S);

  k_head<<<dim3((S + 3) / 4), 256, 0, stream>>>(batch, xywh, W_h, b_h,
                                                out_hp, hxv, hyv, vfv, cxyv, S, F);
  k_prep_w<<<dim3((A * F / 8 + 255) / 256), 256, 0, stream>>>(W_g, WgT, F, A);
  k_targets_mfma<<<dim3(S / 32), 256, 0, stream>>>(batch, WgT, b_g, tgtT, S, F, A);
  k_gather_v3<<<dim3(S / 32), 512, 0, stream>>>(tgtT, cxyv, hxv, hyv, vfv,
                                                out_tw, S, A);
}

// Round 5
// 333.745 us; speedup vs baseline: 2.8503x; 1.0018x over previous
//
#include <hip/hip_runtime.h>
#include <math.h>
#include <stdint.h>

typedef __attribute__((ext_vector_type(8))) short short8;
typedef __attribute__((ext_vector_type(4))) float f32x4;

__device__ __forceinline__ uint32_t cvt_pk_bf16(float lo, float hi) {
  uint32_t r;
  asm("v_cvt_pk_bf16_f32 %0, %1, %2" : "=v"(r) : "v"(lo), "v"(hi));
  return r;
}

// inverse-distance weight; invalid j has cx=cy=1e30 -> d2 overflows to inf
// -> rcp(inf)=0, so invalid columns contribute exactly 0.
__device__ __forceinline__ float wfun(float hx, float hy, float cx, float cy) {
  float dx = hx - cx, dy = hy - cy;
  float d = __builtin_amdgcn_sqrtf(fmaf(dx, dx, dy * dy));
  return __builtin_amdgcn_rcpf(d + 1e-4f);
}

// ---------------------------------------------------------------------------
// Kernel 1: hp = tanh(batch@W_h + b_h); hx,hy,validf,cxy per row. (round-3)
__global__ __launch_bounds__(256) void k_head(
    const float* __restrict__ batch, const float* __restrict__ xywh,
    const float* __restrict__ W_h, const float* __restrict__ b_h,
    float* __restrict__ hp_out, float* __restrict__ hx, float* __restrict__ hy,
    float* __restrict__ validf, float2* __restrict__ cxy, int S, int F) {
  int wid = threadIdx.x >> 6;
  int lane = threadIdx.x & 63;
  int row = blockIdx.x * 4 + wid;
  if (row >= S) return;
  const float4* brow = (const float4*)(batch + (size_t)row * F);
  const float4* wh4 = (const float4*)W_h;  // W_h is [F,2] row-major
  int nf4 = F >> 2;
  float acc0 = 0.f, acc1 = 0.f;
  for (int k4 = lane; k4 < nf4; k4 += 64) {
    float4 b = brow[k4];
    float4 wa = wh4[2 * k4];
    float4 wb = wh4[2 * k4 + 1];
    acc0 += b.x * wa.x + b.y * wa.z + b.z * wb.x + b.w * wb.z;
    acc1 += b.x * wa.y + b.y * wa.w + b.z * wb.y + b.w * wb.w;
  }
  #pragma unroll
  for (int off = 32; off; off >>= 1) {
    acc0 += __shfl_xor(acc0, off, 64);
    acc1 += __shfl_xor(acc1, off, 64);
  }
  if (lane == 0) {
    float hp0 = tanhf(acc0 + b_h[0]);
    float hp1 = tanhf(acc1 + b_h[1]);
    float4 xy = ((const float4*)xywh)[row];
    hp_out[2 * row] = hp0;
    hp_out[2 * row + 1] = hp1;
    hx[row] = hp0 * xy.z * 4.0f + xy.x;  // SIGMA_X = 4
    hy[row] = hp1 * xy.w * 1.0f + xy.y;  // SIGMA_Y = 1
    bool v = (xy.x + xy.y + xy.z + xy.w >= 1e-8f);
    validf[row] = v ? 1.0f : 0.0f;
    cxy[row] = v ? make_float2(xy.x, xy.y) : make_float2(1e30f, 1e30f);
  }
}

// ---------------------------------------------------------------------------
// Kernel 1b: WgT[a][k] = bf16(Wg[k][a])  (round-3, verified)
__global__ __launch_bounds__(256) void k_prep_w(
    const float* __restrict__ Wg, uint16_t* __restrict__ WgT, int F, int A) {
  int idx = blockIdx.x * 256 + threadIdx.x;
  int a = idx % A;
  int k0 = (idx / A) * 8;
  if (k0 >= F) return;
  float f[8];
  #pragma unroll
  for (int e = 0; e < 8; ++e) f[e] = Wg[(size_t)(k0 + e) * A + a];
  uint4 v;
  v.x = cvt_pk_bf16(f[0], f[1]);
  v.y = cvt_pk_bf16(f[2], f[3]);
  v.z = cvt_pk_bf16(f[4], f[5]);
  v.w = cvt_pk_bf16(f[6], f[7]);
  *(uint4*)(WgT + (size_t)a * F + k0) = v;
}

// ---------------------------------------------------------------------------
// Kernel 2: tgtT[a][i] = bf16(relu(batch @ Wg + bg)) via bf16 MFMA (round-3)
__global__ __launch_bounds__(256) void k_targets_mfma(
    const float* __restrict__ batch, const uint16_t* __restrict__ WgT,
    const float* __restrict__ bg, uint16_t* __restrict__ tgtT,
    int S, int F, int A) {
  int t = threadIdx.x;
  int lane = t & 63, wid = t >> 6;
  int wm = wid >> 1, wn = wid & 1;
  int i0 = blockIdx.x * 32;
  int row = i0 + wm * 16 + (lane & 15);
  int kch = lane >> 4;
  const float* ab = batch + (size_t)row * F + kch * 8;
  int ncol0 = wn * 128 + (lane & 15);
  const uint16_t* bb = WgT + (size_t)ncol0 * F + kch * 8;

  f32x4 acc[8] = {};
  float4 a0 = *(const float4*)(ab);
  float4 a1 = *(const float4*)(ab + 4);
  short8 bf[8];
  #pragma unroll
  for (int nf = 0; nf < 8; ++nf)
    bf[nf] = *(const short8*)(bb + (size_t)nf * 16 * F);

  for (int k0 = 0; k0 < F; k0 += 32) {
    int kn = (k0 + 32 < F) ? k0 + 32 : 0;  // wrap prefetch (harmless)
    float4 na0 = *(const float4*)(ab + kn);
    float4 na1 = *(const float4*)(ab + kn + 4);
    short8 nbf[8];
    #pragma unroll
    for (int nf = 0; nf < 8; ++nf)
      nbf[nf] = *(const short8*)(bb + kn + (size_t)nf * 16 * F);
    union { short8 s; uint32_t u[4]; } af;
    af.u[0] = cvt_pk_bf16(a0.x, a0.y);
    af.u[1] = cvt_pk_bf16(a0.z, a0.w);
    af.u[2] = cvt_pk_bf16(a1.x, a1.y);
    af.u[3] = cvt_pk_bf16(a1.z, a1.w);
    #pragma unroll
    for (int nf = 0; nf < 8; ++nf)
      acc[nf] = __builtin_amdgcn_mfma_f32_16x16x32_bf16(af.s, bf[nf], acc[nf], 0, 0, 0);
    a0 = na0; a1 = na1;
    #pragma unroll
    for (int nf = 0; nf < 8; ++nf) bf[nf] = nbf[nf];
  }

  int rbase = i0 + wm * 16 + (lane >> 4) * 4;
  #pragma unroll
  for (int nf = 0; nf < 8; ++nf) {
    int col = ncol0 + nf * 16;
    float b = bg[col];
    float o0 = fmaxf(acc[nf][0] + b, 0.f);
    float o1 = fmaxf(acc[nf][1] + b, 0.f);
    float o2 = fmaxf(acc[nf][2] + b, 0.f);
    float o3 = fmaxf(acc[nf][3] + b, 0.f);
    uint2 pk;
    pk.x = cvt_pk_bf16(o0, o1);
    pk.y = cvt_pk_bf16(o2, o3);
    *(uint2*)(tgtT + (size_t)col * S + rbase) = pk;
  }
}

// ---------------------------------------------------------------------------
// Kernel 3: out = rownorm(W) @ targets. Round-3 per-lane w-gen body VERBATIM,
// but 1024 threads = 16 waves = 2(Kgroup) x 2(M) x 4(N): each K-group runs
// the round-3 loop over HALF the j range (128 steps). Partial acc + rowsums
// combined through LDS at the end. 4 waves/SIMD (2x round 3).
__global__ __launch_bounds__(1024, 4) void k_gather_v5(
    const uint16_t* __restrict__ tgtT, const float2* __restrict__ cxy,
    const float* __restrict__ hx, const float* __restrict__ hy,
    const float* __restrict__ validf, float* __restrict__ out, int S, int A) {
  __shared__ float comb[32][257];   // kg=1 partial acc, [row][col]
  __shared__ float rs2[2][32];      // per-kg row sums
  __shared__ float scale_s[32];
  int t = threadIdx.x;
  int lane = t & 63, wid = t >> 6;
  int kg = wid >> 3;
  int sub = wid & 7;
  int wm = sub >> 2, wn = sub & 3;  // 2M x 4N within K-group
  int i0 = blockIdx.x * 32;
  int mrow = i0 + wm * 16 + (lane & 15);
  int kch = lane >> 4;
  float hx_i = hx[mrow], hy_i = hy[mrow];
  int n0 = wn * 64 + (lane & 15);
  int jbase = kg * (S >> 1);
  const uint16_t* bbase = tgtT + (size_t)n0 * S + jbase + kch * 8;
  const float2* cbase = cxy + jbase + kch * 8;

  f32x4 acc[4] = {};
  float rs = 0.f;

  // prefetch step 0 (round-3 pattern)
  float4 c0 = *(const float4*)(cbase);
  float4 c1 = *(const float4*)(cbase + 2);
  float4 c2 = *(const float4*)(cbase + 4);
  float4 c3 = *(const float4*)(cbase + 6);
  short8 b0 = *(const short8*)(bbase);
  short8 b1 = *(const short8*)(bbase + (size_t)16 * S);
  short8 b2 = *(const short8*)(bbase + (size_t)32 * S);
  short8 b3 = *(const short8*)(bbase + (size_t)48 * S);

  int nsteps = (S >> 1) / 32;   // 128
  for (int ts = 0; ts < nsteps; ++ts) {
    int jn = (ts + 1 < nsteps) ? (ts + 1) * 32 : 0;  // wrap prefetch
    const float4* cpn = (const float4*)(cbase + jn);
    float4 nc0 = cpn[0];
    float4 nc1 = cpn[1];
    float4 nc2 = cpn[2];
    float4 nc3 = cpn[3];
    const uint16_t* bpn = bbase + jn;
    short8 nb0 = *(const short8*)(bpn);
    short8 nb1 = *(const short8*)(bpn + (size_t)16 * S);
    short8 nb2 = *(const short8*)(bpn + (size_t)32 * S);
    short8 nb3 = *(const short8*)(bpn + (size_t)48 * S);

    // 8 w's for this lane's A fragment (row=lane&15, k=(lane>>4)*8+e)
    float w0 = wfun(hx_i, hy_i, c0.x, c0.y);
    float w1 = wfun(hx_i, hy_i, c0.z, c0.w);
    float w2 = wfun(hx_i, hy_i, c1.x, c1.y);
    float w3 = wfun(hx_i, hy_i, c1.z, c1.w);
    float w4 = wfun(hx_i, hy_i, c2.x, c2.y);
    float w5 = wfun(hx_i, hy_i, c2.z, c2.w);
    float w6 = wfun(hx_i, hy_i, c3.x, c3.y);
    float w7 = wfun(hx_i, hy_i, c3.z, c3.w);
    rs += ((w0 + w1) + (w2 + w3)) + ((w4 + w5) + (w6 + w7));
    union { short8 s; uint32_t u[4]; } af;
    af.u[0] = cvt_pk_bf16(w0, w1);
    af.u[1] = cvt_pk_bf16(w2, w3);
    af.u[2] = cvt_pk_bf16(w4, w5);
    af.u[3] = cvt_pk_bf16(w6, w7);

    acc[0] = __builtin_amdgcn_mfma_f32_16x16x32_bf16(af.s, b0, acc[0], 0, 0, 0);
    acc[1] = __builtin_amdgcn_mfma_f32_16x16x32_bf16(af.s, b1, acc[1], 0, 0, 0);
    acc[2] = __builtin_amdgcn_mfma_f32_16x16x32_bf16(af.s, b2, acc[2], 0, 0, 0);
    acc[3] = __builtin_amdgcn_mfma_f32_16x16x32_bf16(af.s, b3, acc[3], 0, 0, 0);

    c0 = nc0; c1 = nc1; c2 = nc2; c3 = nc3;
    b0 = nb0; b1 = nb1; b2 = nb2; b3 = nb3;
  }

  // per-kg row sums: combine the 4 kch groups (wn waves hold identical sums)
  rs += __shfl_xor(rs, 16, 64);
  rs += __shfl_xor(rs, 32, 64);
  if (wn == 0 && lane < 16) rs2[kg][wm * 16 + lane] = rs;

  // kg=1 publishes its partial acc
  if (kg == 1) {
    int mre = wm * 16 + (lane >> 4) * 4;
    #pragma unroll
    for (int r = 0; r < 4; ++r) {
      comb[mre + r][n0]      = acc[0][r];
      comb[mre + r][n0 + 16] = acc[1][r];
      comb[mre + r][n0 + 32] = acc[2][r];
      comb[mre + r][n0 + 48] = acc[3][r];
    }
  }
  __syncthreads();
  if (t < 32) {
    float r = rs2[0][t] + rs2[1][t];
    float v = validf[i0 + t];
    scale_s[t] = (v > 0.f) ? 1.0f / fmaxf(r, 1e-30f) : 0.f;
  }
  __syncthreads();
  if (kg == 0) {
    int mre = wm * 16 + (lane >> 4) * 4;
    #pragma unroll
    for (int r = 0; r < 4; ++r) {
      float s = scale_s[mre + r];
      size_t base = (size_t)(i0 + mre + r) * A;
      out[base + n0]      = (acc[0][r] + comb[mre + r][n0]) * s;
      out[base + n0 + 16] = (acc[1][r] + comb[mre + r][n0 + 16]) * s;
      out[base + n0 + 32] = (acc[2][r] + comb[mre + r][n0 + 32]) * s;
      out[base + n0 + 48] = (acc[3][r] + comb[mre + r][n0 + 48]) * s;
    }
  }
}

extern "C" void kernel_launch(void* const* d_in, const int* in_sizes, int n_in,
                              void* d_out, int out_size, void* d_ws, size_t ws_size,
                              hipStream_t stream) {
  // inputs: 0 batch[S,F] 1 xywh[S,4] 2 OW 3 OH 4 actor_weights[S] 5 avg_pos[S,2]
  //         6 W_h[F,2] 7 b_h[2] 8 W_g[F,A] 9 b_g[A] 10 num_person
  const float* batch = (const float*)d_in[0];
  const float* xywh  = (const float*)d_in[1];
  const float* W_h   = (const float*)d_in[6];
  const float* b_h   = (const float*)d_in[7];
  const float* W_g   = (const float*)d_in[8];
  const float* b_g   = (const float*)d_in[9];
  int S = in_sizes[4];
  int F = in_sizes[0] / S;
  int A = in_sizes[9];

  float* out    = (float*)d_out;
  float* out_tw = out;                        // [S,A]
  float* out_hp = out + (size_t)S * A;        // [S,2]

  // workspace: tgtT bf16 [A][S], WgT bf16 [A][F], hx/hy/validf [S], cxy [S,2]
  uint16_t* tgtT = (uint16_t*)d_ws;
  uint16_t* WgT  = tgtT + (size_t)A * S;
  float* hxv = (float*)(WgT + (size_t)A * F);
  float* hyv = hxv + S;
  float* vfv = hyv + S;
  float2* cxyv = (float2*)(vfv + S);

  k_head<<<dim3((S + 3) / 4), 256, 0, stream>>>(batch, xywh, W_h, b_h,
                                                out_hp, hxv, hyv, vfv, cxyv, S, F);
  k_prep_w<<<dim3((A * F / 8 + 255) / 256), 256, 0, stream>>>(W_g, WgT, F, A);
  k_targets_mfma<<<dim3(S / 32), 256, 0, stream>>>(batch, WgT, b_g, tgtT, S, F, A);
  k_gather_v5<<<dim3(S / 32), 1024, 0, stream>>>(tgtT, cxyv, hxv, hyv, vfv,
                                                 out_tw, S, A);
}

// Round 6
// 224.265 us; speedup vs baseline: 4.2417x; 1.4882x over previous
//
#include <hip/hip_runtime.h>
#include <math.h>
#include <stdint.h>

typedef __attribute__((ext_vector_type(8))) short short8;
typedef __attribute__((ext_vector_type(4))) float f32x4;

__device__ __forceinline__ uint32_t cvt_pk_bf16(float lo, float hi) {
  uint32_t r;
  asm("v_cvt_pk_bf16_f32 %0, %1, %2" : "=v"(r) : "v"(lo), "v"(hi));
  return r;
}

// inverse-distance weight; invalid j has cx=cy=1e30 -> d2 overflows to inf
// -> rcp(inf)=0, so invalid columns contribute exactly 0.
__device__ __forceinline__ float wfun(float hx, float hy, float cx, float cy) {
  float dx = hx - cx, dy = hy - cy;
  float d = __builtin_amdgcn_sqrtf(fmaf(dx, dx, dy * dy));
  return __builtin_amdgcn_rcpf(d + 1e-4f);
}

// ---------------------------------------------------------------------------
// Kernel 1: hp = tanh(batch@W_h + b_h); hx,hy,validf,cxy per row. (verified)
__global__ __launch_bounds__(256) void k_head(
    const float* __restrict__ batch, const float* __restrict__ xywh,
    const float* __restrict__ W_h, const float* __restrict__ b_h,
    float* __restrict__ hp_out, float* __restrict__ hx, float* __restrict__ hy,
    float* __restrict__ validf, float2* __restrict__ cxy, int S, int F) {
  int wid = threadIdx.x >> 6;
  int lane = threadIdx.x & 63;
  int row = blockIdx.x * 4 + wid;
  if (row >= S) return;
  const float4* brow = (const float4*)(batch + (size_t)row * F);
  const float4* wh4 = (const float4*)W_h;  // W_h is [F,2] row-major
  int nf4 = F >> 2;
  float acc0 = 0.f, acc1 = 0.f;
  for (int k4 = lane; k4 < nf4; k4 += 64) {
    float4 b = brow[k4];
    float4 wa = wh4[2 * k4];
    float4 wb = wh4[2 * k4 + 1];
    acc0 += b.x * wa.x + b.y * wa.z + b.z * wb.x + b.w * wb.z;
    acc1 += b.x * wa.y + b.y * wa.w + b.z * wb.y + b.w * wb.w;
  }
  #pragma unroll
  for (int off = 32; off; off >>= 1) {
    acc0 += __shfl_xor(acc0, off, 64);
    acc1 += __shfl_xor(acc1, off, 64);
  }
  if (lane == 0) {
    float hp0 = tanhf(acc0 + b_h[0]);
    float hp1 = tanhf(acc1 + b_h[1]);
    float4 xy = ((const float4*)xywh)[row];
    hp_out[2 * row] = hp0;
    hp_out[2 * row + 1] = hp1;
    hx[row] = hp0 * xy.z * 4.0f + xy.x;  // SIGMA_X = 4
    hy[row] = hp1 * xy.w * 1.0f + xy.y;  // SIGMA_Y = 1
    bool v = (xy.x + xy.y + xy.z + xy.w >= 1e-8f);
    validf[row] = v ? 1.0f : 0.0f;
    cxy[row] = v ? make_float2(xy.x, xy.y) : make_float2(1e30f, 1e30f);
  }
}

// ---------------------------------------------------------------------------
// Kernel 1b: WgT[a][k] = bf16(Wg[k][a])  (verified)
__global__ __launch_bounds__(256) void k_prep_w(
    const float* __restrict__ Wg, uint16_t* __restrict__ WgT, int F, int A) {
  int idx = blockIdx.x * 256 + threadIdx.x;
  int a = idx % A;
  int k0 = (idx / A) * 8;
  if (k0 >= F) return;
  float f[8];
  #pragma unroll
  for (int e = 0; e < 8; ++e) f[e] = Wg[(size_t)(k0 + e) * A + a];
  uint4 v;
  v.x = cvt_pk_bf16(f[0], f[1]);
  v.y = cvt_pk_bf16(f[2], f[3]);
  v.z = cvt_pk_bf16(f[4], f[5]);
  v.w = cvt_pk_bf16(f[6], f[7]);
  *(uint4*)(WgT + (size_t)a * F + k0) = v;
}

// ---------------------------------------------------------------------------
// Kernel 2: targets via bf16 MFMA (verified body); OUTPUT LAYOUT CHANGED:
// tgt2[jb][a][jj], jb = i/32, jj = i%32  -> B-frag loads become contiguous
// (kills the 16 KB power-of-2 row stride that serialized L2 channels).
__global__ __launch_bounds__(256) void k_targets_mfma(
    const float* __restrict__ batch, const uint16_t* __restrict__ WgT,
    const float* __restrict__ bg, uint16_t* __restrict__ tgt2,
    int S, int F, int A) {
  int t = threadIdx.x;
  int lane = t & 63, wid = t >> 6;
  int wm = wid >> 1, wn = wid & 1;
  int i0 = blockIdx.x * 32;
  int row = i0 + wm * 16 + (lane & 15);
  int kch = lane >> 4;
  const float* ab = batch + (size_t)row * F + kch * 8;
  int ncol0 = wn * 128 + (lane & 15);
  const uint16_t* bb = WgT + (size_t)ncol0 * F + kch * 8;

  f32x4 acc[8] = {};
  float4 a0 = *(const float4*)(ab);
  float4 a1 = *(const float4*)(ab + 4);
  short8 bf[8];
  #pragma unroll
  for (int nf = 0; nf < 8; ++nf)
    bf[nf] = *(const short8*)(bb + (size_t)nf * 16 * F);

  for (int k0 = 0; k0 < F; k0 += 32) {
    int kn = (k0 + 32 < F) ? k0 + 32 : 0;  // wrap prefetch (harmless)
    float4 na0 = *(const float4*)(ab + kn);
    float4 na1 = *(const float4*)(ab + kn + 4);
    short8 nbf[8];
    #pragma unroll
    for (int nf = 0; nf < 8; ++nf)
      nbf[nf] = *(const short8*)(bb + kn + (size_t)nf * 16 * F);
    union { short8 s; uint32_t u[4]; } af;
    af.u[0] = cvt_pk_bf16(a0.x, a0.y);
    af.u[1] = cvt_pk_bf16(a0.z, a0.w);
    af.u[2] = cvt_pk_bf16(a1.x, a1.y);
    af.u[3] = cvt_pk_bf16(a1.z, a1.w);
    #pragma unroll
    for (int nf = 0; nf < 8; ++nf)
      acc[nf] = __builtin_amdgcn_mfma_f32_16x16x32_bf16(af.s, bf[nf], acc[nf], 0, 0, 0);
    a0 = na0; a1 = na1;
    #pragma unroll
    for (int nf = 0; nf < 8; ++nf) bf[nf] = nbf[nf];
  }

  // this block covers exactly tile jb = blockIdx.x (rows i0..i0+31)
  int jb = blockIdx.x;
  int rloc = wm * 16 + (lane >> 4) * 4;   // row within tile, mult of 4
  #pragma unroll
  for (int nf = 0; nf < 8; ++nf) {
    int col = ncol0 + nf * 16;
    float b = bg[col];
    float o0 = fmaxf(acc[nf][0] + b, 0.f);
    float o1 = fmaxf(acc[nf][1] + b, 0.f);
    float o2 = fmaxf(acc[nf][2] + b, 0.f);
    float o3 = fmaxf(acc[nf][3] + b, 0.f);
    uint2 pk;
    pk.x = cvt_pk_bf16(o0, o1);
    pk.y = cvt_pk_bf16(o2, o3);
    *(uint2*)(tgt2 + ((size_t)jb * A + col) * 32 + rloc) = pk;
  }
}

// ---------------------------------------------------------------------------
// Kernel 3: out = rownorm(W) @ targets.  (round-5 verified structure; only
// the B-operand addressing changed to the tiled tgt2 layout.)
// 1024 threads = 16 waves = 2(Kgroup) x 2(M) x 4(N). Per step, a wave's 4
// B-loads cover 4 consecutive KB of tgt2 -> fully coalesced L2 streaming.
__global__ __launch_bounds__(1024, 4) void k_gather_v6(
    const uint16_t* __restrict__ tgt2, const float2* __restrict__ cxy,
    const float* __restrict__ hx, const float* __restrict__ hy,
    const float* __restrict__ validf, float* __restrict__ out, int S, int A) {
  __shared__ float comb[32][257];   // kg=1 partial acc, [row][col]
  __shared__ float rs2[2][32];      // per-kg row sums
  __shared__ float scale_s[32];
  int t = threadIdx.x;
  int lane = t & 63, wid = t >> 6;
  int kg = wid >> 3;
  int sub = wid & 7;
  int wm = sub >> 2, wn = sub & 3;  // 2M x 4N within K-group
  int i0 = blockIdx.x * 32;
  int mrow = i0 + wm * 16 + (lane & 15);
  int kch = lane >> 4;
  float hx_i = hx[mrow], hy_i = hy[mrow];
  int n0 = wn * 64 + (lane & 15);
  int nsteps = (S >> 1) / 32;                  // 128 tiles per K-group
  int jb0 = kg * nsteps;                       // first tile of this K-group
  int jbase = kg * (S >> 1);
  const size_t TSTRIDE = (size_t)A * 32;       // elements per j-tile
  const uint16_t* bbase = tgt2 + (size_t)jb0 * TSTRIDE + (size_t)n0 * 32 + kch * 8;
  const float2* cbase = cxy + jbase + kch * 8;

  f32x4 acc[4] = {};
  float rs = 0.f;

  // prefetch step 0
  float4 c0 = *(const float4*)(cbase);
  float4 c1 = *(const float4*)(cbase + 2);
  float4 c2 = *(const float4*)(cbase + 4);
  float4 c3 = *(const float4*)(cbase + 6);
  short8 b0 = *(const short8*)(bbase);
  short8 b1 = *(const short8*)(bbase + 512);   // +16 cols * 32
  short8 b2 = *(const short8*)(bbase + 1024);
  short8 b3 = *(const short8*)(bbase + 1536);

  for (int ts = 0; ts < nsteps; ++ts) {
    int tn = (ts + 1 < nsteps) ? ts + 1 : 0;   // next tile (wrap prefetch)
    const float4* cpn = (const float4*)(cbase + tn * 32);
    float4 nc0 = cpn[0];
    float4 nc1 = cpn[1];
    float4 nc2 = cpn[2];
    float4 nc3 = cpn[3];
    const uint16_t* bp = bbase + (size_t)tn * TSTRIDE;
    short8 nb0 = *(const short8*)(bp);
    short8 nb1 = *(const short8*)(bp + 512);
    short8 nb2 = *(const short8*)(bp + 1024);
    short8 nb3 = *(const short8*)(bp + 1536);

    // 8 w's for this lane's A fragment (row=lane&15, k=(lane>>4)*8+e)
    float w0 = wfun(hx_i, hy_i, c0.x, c0.y);
    float w1 = wfun(hx_i, hy_i, c0.z, c0.w);
    float w2 = wfun(hx_i, hy_i, c1.x, c1.y);
    float w3 = wfun(hx_i, hy_i, c1.z, c1.w);
    float w4 = wfun(hx_i, hy_i, c2.x, c2.y);
    float w5 = wfun(hx_i, hy_i, c2.z, c2.w);
    float w6 = wfun(hx_i, hy_i, c3.x, c3.y);
    float w7 = wfun(hx_i, hy_i, c3.z, c3.w);
    rs += ((w0 + w1) + (w2 + w3)) + ((w4 + w5) + (w6 + w7));
    union { short8 s; uint32_t u[4]; } af;
    af.u[0] = cvt_pk_bf16(w0, w1);
    af.u[1] = cvt_pk_bf16(w2, w3);
    af.u[2] = cvt_pk_bf16(w4, w5);
    af.u[3] = cvt_pk_bf16(w6, w7);

    acc[0] = __builtin_amdgcn_mfma_f32_16x16x32_bf16(af.s, b0, acc[0], 0, 0, 0);
    acc[1] = __builtin_amdgcn_mfma_f32_16x16x32_bf16(af.s, b1, acc[1], 0, 0, 0);
    acc[2] = __builtin_amdgcn_mfma_f32_16x16x32_bf16(af.s, b2, acc[2], 0, 0, 0);
    acc[3] = __builtin_amdgcn_mfma_f32_16x16x32_bf16(af.s, b3, acc[3], 0, 0, 0);

    c0 = nc0; c1 = nc1; c2 = nc2; c3 = nc3;
    b0 = nb0; b1 = nb1; b2 = nb2; b3 = nb3;
  }

  // per-kg row sums: combine the 4 kch groups (wn waves hold identical sums)
  rs += __shfl_xor(rs, 16, 64);
  rs += __shfl_xor(rs, 32, 64);
  if (wn == 0 && lane < 16) rs2[kg][wm * 16 + lane] = rs;

  // kg=1 publishes its partial acc
  if (kg == 1) {
    int mre = wm * 16 + (lane >> 4) * 4;
    #pragma unroll
    for (int r = 0; r < 4; ++r) {
      comb[mre + r][n0]      = acc[0][r];
      comb[mre + r][n0 + 16] = acc[1][r];
      comb[mre + r][n0 + 32] = acc[2][r];
      comb[mre + r][n0 + 48] = acc[3][r];
    }
  }
  __syncthreads();
  if (t < 32) {
    float r = rs2[0][t] + rs2[1][t];
    float v = validf[i0 + t];
    scale_s[t] = (v > 0.f) ? 1.0f / fmaxf(r, 1e-30f) : 0.f;
  }
  __syncthreads();
  if (kg == 0) {
    int mre = wm * 16 + (lane >> 4) * 4;
    #pragma unroll
    for (int r = 0; r < 4; ++r) {
      float s = scale_s[mre + r];
      size_t base = (size_t)(i0 + mre + r) * A;
      out[base + n0]      = (acc[0][r] + comb[mre + r][n0]) * s;
      out[base + n0 + 16] = (acc[1][r] + comb[mre + r][n0 + 16]) * s;
      out[base + n0 + 32] = (acc[2][r] + comb[mre + r][n0 + 32]) * s;
      out[base + n0 + 48] = (acc[3][r] + comb[mre + r][n0 + 48]) * s;
    }
  }
}

extern "C" void kernel_launch(void* const* d_in, const int* in_sizes, int n_in,
                              void* d_out, int out_size, void* d_ws, size_t ws_size,
                              hipStream_t stream) {
  // inputs: 0 batch[S,F] 1 xywh[S,4] 2 OW 3 OH 4 actor_weights[S] 5 avg_pos[S,2]
  //         6 W_h[F,2] 7 b_h[2] 8 W_g[F,A] 9 b_g[A] 10 num_person
  const float* batch = (const float*)d_in[0];
  const float* xywh  = (const float*)d_in[1];
  const float* W_h   = (const float*)d_in[6];
  const float* b_h   = (const float*)d_in[7];
  const float* W_g   = (const float*)d_in[8];
  const float* b_g   = (const float*)d_in[9];
  int S = in_sizes[4];
  int F = in_sizes[0] / S;
  int A = in_sizes[9];

  float* out    = (float*)d_out;
  float* out_tw = out;                        // [S,A]
  float* out_hp = out + (size_t)S * A;        // [S,2]

  // workspace: tgt2 bf16 [S/32][A][32], WgT bf16 [A][F], hx/hy/validf, cxy
  uint16_t* tgt2 = (uint16_t*)d_ws;
  uint16_t* WgT  = tgt2 + (size_t)A * S;
  float* hxv = (float*)(WgT + (size_t)A * F);
  float* hyv = hxv + S;
  float* vfv = hyv + S;
  float2* cxyv = (float2*)(vfv + S);

  k_head<<<dim3((S + 3) / 4), 256, 0, stream>>>(batch, xywh, W_h, b_h,
                                                out_hp, hxv, hyv, vfv, cxyv, S, F);
  k_prep_w<<<dim3((A * F / 8 + 255) / 256), 256, 0, stream>>>(W_g, WgT, F, A);
  k_targets_mfma<<<dim3(S / 32), 256, 0, stream>>>(batch, WgT, b_g, tgt2, S, F, A);
  k_gather_v6<<<dim3(S / 32), 1024, 0, stream>>>(tgt2, cxyv, hxv, hyv, vfv,
                                                 out_tw, S, A);
}

// Round 7
// 222.975 us; speedup vs baseline: 4.2662x; 1.0058x over previous
//
#include <hip/hip_runtime.h>
#include <math.h>
#include <stdint.h>

typedef __attribute__((ext_vector_type(8))) short short8;
typedef __attribute__((ext_vector_type(4))) float f32x4;

__device__ __forceinline__ uint32_t cvt_pk_bf16(float lo, float hi) {
  uint32_t r;
  asm("v_cvt_pk_bf16_f32 %0, %1, %2" : "=v"(r) : "v"(lo), "v"(hi));
  return r;
}

// inverse-distance weight; invalid j has cx=cy=1e30 -> d2 overflows to inf
// -> rcp(inf)=0, so invalid columns contribute exactly 0.
__device__ __forceinline__ float wfun(float hx, float hy, float cx, float cy) {
  float dx = hx - cx, dy = hy - cy;
  float d = __builtin_amdgcn_sqrtf(fmaf(dx, dx, dy * dy));
  return __builtin_amdgcn_rcpf(d + 1e-4f);
}

// ---------------------------------------------------------------------------
// Kernel 1: hp = tanh(batch@W_h + b_h); hx,hy,validf,cxy per row. (verified)
__global__ __launch_bounds__(256) void k_head(
    const float* __restrict__ batch, const float* __restrict__ xywh,
    const float* __restrict__ W_h, const float* __restrict__ b_h,
    float* __restrict__ hp_out, float* __restrict__ hx, float* __restrict__ hy,
    float* __restrict__ validf, float2* __restrict__ cxy, int S, int F) {
  int wid = threadIdx.x >> 6;
  int lane = threadIdx.x & 63;
  int row = blockIdx.x * 4 + wid;
  if (row >= S) return;
  const float4* brow = (const float4*)(batch + (size_t)row * F);
  const float4* wh4 = (const float4*)W_h;  // W_h is [F,2] row-major
  int nf4 = F >> 2;
  float acc0 = 0.f, acc1 = 0.f;
  for (int k4 = lane; k4 < nf4; k4 += 64) {
    float4 b = brow[k4];
    float4 wa = wh4[2 * k4];
    float4 wb = wh4[2 * k4 + 1];
    acc0 += b.x * wa.x + b.y * wa.z + b.z * wb.x + b.w * wb.z;
    acc1 += b.x * wa.y + b.y * wa.w + b.z * wb.y + b.w * wb.w;
  }
  #pragma unroll
  for (int off = 32; off; off >>= 1) {
    acc0 += __shfl_xor(acc0, off, 64);
    acc1 += __shfl_xor(acc1, off, 64);
  }
  if (lane == 0) {
    float hp0 = tanhf(acc0 + b_h[0]);
    float hp1 = tanhf(acc1 + b_h[1]);
    float4 xy = ((const float4*)xywh)[row];
    hp_out[2 * row] = hp0;
    hp_out[2 * row + 1] = hp1;
    hx[row] = hp0 * xy.z * 4.0f + xy.x;  // SIGMA_X = 4
    hy[row] = hp1 * xy.w * 1.0f + xy.y;  // SIGMA_Y = 1
    bool v = (xy.x + xy.y + xy.z + xy.w >= 1e-8f);
    validf[row] = v ? 1.0f : 0.0f;
    cxy[row] = v ? make_float2(xy.x, xy.y) : make_float2(1e30f, 1e30f);
  }
}

// ---------------------------------------------------------------------------
// Kernel 1b: WgT[a][k] = bf16(Wg[k][a])  (verified)
__global__ __launch_bounds__(256) void k_prep_w(
    const float* __restrict__ Wg, uint16_t* __restrict__ WgT, int F, int A) {
  int idx = blockIdx.x * 256 + threadIdx.x;
  int a = idx % A;
  int k0 = (idx / A) * 8;
  if (k0 >= F) return;
  float f[8];
  #pragma unroll
  for (int e = 0; e < 8; ++e) f[e] = Wg[(size_t)(k0 + e) * A + a];
  uint4 v;
  v.x = cvt_pk_bf16(f[0], f[1]);
  v.y = cvt_pk_bf16(f[2], f[3]);
  v.z = cvt_pk_bf16(f[4], f[5]);
  v.w = cvt_pk_bf16(f[6], f[7]);
  *(uint4*)(WgT + (size_t)a * F + k0) = v;
}

// ---------------------------------------------------------------------------
// Kernel 2: targets via bf16 MFMA; tiled output tgt2[jb][a][jj]. (verified)
__global__ __launch_bounds__(256) void k_targets_mfma(
    const float* __restrict__ batch, const uint16_t* __restrict__ WgT,
    const float* __restrict__ bg, uint16_t* __restrict__ tgt2,
    int S, int F, int A) {
  int t = threadIdx.x;
  int lane = t & 63, wid = t >> 6;
  int wm = wid >> 1, wn = wid & 1;
  int i0 = blockIdx.x * 32;
  int row = i0 + wm * 16 + (lane & 15);
  int kch = lane >> 4;
  const float* ab = batch + (size_t)row * F + kch * 8;
  int ncol0 = wn * 128 + (lane & 15);
  const uint16_t* bb = WgT + (size_t)ncol0 * F + kch * 8;

  f32x4 acc[8] = {};
  float4 a0 = *(const float4*)(ab);
  float4 a1 = *(const float4*)(ab + 4);
  short8 bf[8];
  #pragma unroll
  for (int nf = 0; nf < 8; ++nf)
    bf[nf] = *(const short8*)(bb + (size_t)nf * 16 * F);

  for (int k0 = 0; k0 < F; k0 += 32) {
    int kn = (k0 + 32 < F) ? k0 + 32 : 0;  // wrap prefetch (harmless)
    float4 na0 = *(const float4*)(ab + kn);
    float4 na1 = *(const float4*)(ab + kn + 4);
    short8 nbf[8];
    #pragma unroll
    for (int nf = 0; nf < 8; ++nf)
      nbf[nf] = *(const short8*)(bb + kn + (size_t)nf * 16 * F);
    union { short8 s; uint32_t u[4]; } af;
    af.u[0] = cvt_pk_bf16(a0.x, a0.y);
    af.u[1] = cvt_pk_bf16(a0.z, a0.w);
    af.u[2] = cvt_pk_bf16(a1.x, a1.y);
    af.u[3] = cvt_pk_bf16(a1.z, a1.w);
    #pragma unroll
    for (int nf = 0; nf < 8; ++nf)
      acc[nf] = __builtin_amdgcn_mfma_f32_16x16x32_bf16(af.s, bf[nf], acc[nf], 0, 0, 0);
    a0 = na0; a1 = na1;
    #pragma unroll
    for (int nf = 0; nf < 8; ++nf) bf[nf] = nbf[nf];
  }

  int jb = blockIdx.x;
  int rloc = wm * 16 + (lane >> 4) * 4;   // row within tile, mult of 4
  #pragma unroll
  for (int nf = 0; nf < 8; ++nf) {
    int col = ncol0 + nf * 16;
    float b = bg[col];
    float o0 = fmaxf(acc[nf][0] + b, 0.f);
    float o1 = fmaxf(acc[nf][1] + b, 0.f);
    float o2 = fmaxf(acc[nf][2] + b, 0.f);
    float o3 = fmaxf(acc[nf][3] + b, 0.f);
    uint2 pk;
    pk.x = cvt_pk_bf16(o0, o1);
    pk.y = cvt_pk_bf16(o2, o3);
    *(uint2*)(tgt2 + ((size_t)jb * A + col) * 32 + rloc) = pk;
  }
}

// ---------------------------------------------------------------------------
// Kernel 3: out = rownorm(W) @ targets. v6 wave body verbatim; block geometry
// changed to BM=64 x BN=128: 16 waves = 2(kg) x 4(wm) x 2(wn), grid =
// (2 col-halves, S/64). Halves total B-traffic (each block reads 2 MB of
// tgt2, 512 MB total) and doubles B-frag L1 sharing (4 wm-waves).
__global__ __launch_bounds__(1024, 4) void k_gather_v7(
    const uint16_t* __restrict__ tgt2, const float2* __restrict__ cxy,
    const float* __restrict__ hx, const float* __restrict__ hy,
    const float* __restrict__ validf, float* __restrict__ out, int S, int A) {
  __shared__ float comb[64][132];   // kg=1 partial acc, [row][col] (33.8 KB)
  __shared__ float rs2[2][64];      // per-kg row sums
  __shared__ float scale_s[64];
  int t = threadIdx.x;
  int lane = t & 63, wid = t >> 6;
  int kg = wid >> 3;                // 0..1
  int sub = wid & 7;
  int wm = sub >> 1, wn = sub & 1;  // 4M x 2N within K-group
  int colhalf = blockIdx.x;         // 0..1
  int i0 = blockIdx.y * 64;
  int mrow = i0 + wm * 16 + (lane & 15);
  int kch = lane >> 4;
  float hx_i = hx[mrow], hy_i = hy[mrow];
  int n0 = wn * 64 + (lane & 15);              // col within block (0..127)
  int acol = colhalf * 128 + n0;               // absolute a-col
  int nsteps = (S >> 1) / 32;                  // 128 tiles per K-group
  int jb0 = kg * nsteps;
  int jbase = kg * (S >> 1);
  const size_t TSTRIDE = (size_t)A * 32;       // elements per j-tile
  const uint16_t* bbase = tgt2 + (size_t)jb0 * TSTRIDE + (size_t)acol * 32 + kch * 8;
  const float2* cbase = cxy + jbase + kch * 8;

  f32x4 acc[4] = {};
  float rs = 0.f;

  // prefetch step 0
  float4 c0 = *(const float4*)(cbase);
  float4 c1 = *(const float4*)(cbase + 2);
  float4 c2 = *(const float4*)(cbase + 4);
  float4 c3 = *(const float4*)(cbase + 6);
  short8 b0 = *(const short8*)(bbase);
  short8 b1 = *(const short8*)(bbase + 512);   // +16 cols * 32
  short8 b2 = *(const short8*)(bbase + 1024);
  short8 b3 = *(const short8*)(bbase + 1536);

  for (int ts = 0; ts < nsteps; ++ts) {
    int tn = (ts + 1 < nsteps) ? ts + 1 : 0;   // next tile (wrap prefetch)
    const float4* cpn = (const float4*)(cbase + tn * 32);
    float4 nc0 = cpn[0];
    float4 nc1 = cpn[1];
    float4 nc2 = cpn[2];
    float4 nc3 = cpn[3];
    const uint16_t* bp = bbase + (size_t)tn * TSTRIDE;
    short8 nb0 = *(const short8*)(bp);
    short8 nb1 = *(const short8*)(bp + 512);
    short8 nb2 = *(const short8*)(bp + 1024);
    short8 nb3 = *(const short8*)(bp + 1536);

    // 8 w's for this lane's A fragment (row=lane&15, k=(lane>>4)*8+e)
    float w0 = wfun(hx_i, hy_i, c0.x, c0.y);
    float w1 = wfun(hx_i, hy_i, c0.z, c0.w);
    float w2 = wfun(hx_i, hy_i, c1.x, c1.y);
    float w3 = wfun(hx_i, hy_i, c1.z, c1.w);
    float w4 = wfun(hx_i, hy_i, c2.x, c2.y);
    float w5 = wfun(hx_i, hy_i, c2.z, c2.w);
    float w6 = wfun(hx_i, hy_i, c3.x, c3.y);
    float w7 = wfun(hx_i, hy_i, c3.z, c3.w);
    rs += ((w0 + w1) + (w2 + w3)) + ((w4 + w5) + (w6 + w7));
    union { short8 s; uint32_t u[4]; } af;
    af.u[0] = cvt_pk_bf16(w0, w1);
    af.u[1] = cvt_pk_bf16(w2, w3);
    af.u[2] = cvt_pk_bf16(w4, w5);
    af.u[3] = cvt_pk_bf16(w6, w7);

    acc[0] = __builtin_amdgcn_mfma_f32_16x16x32_bf16(af.s, b0, acc[0], 0, 0, 0);
    acc[1] = __builtin_amdgcn_mfma_f32_16x16x32_bf16(af.s, b1, acc[1], 0, 0, 0);
    acc[2] = __builtin_amdgcn_mfma_f32_16x16x32_bf16(af.s, b2, acc[2], 0, 0, 0);
    acc[3] = __builtin_amdgcn_mfma_f32_16x16x32_bf16(af.s, b3, acc[3], 0, 0, 0);

    c0 = nc0; c1 = nc1; c2 = nc2; c3 = nc3;
    b0 = nb0; b1 = nb1; b2 = nb2; b3 = nb3;
  }

  // per-kg row sums: combine the 4 kch groups (wn waves hold identical sums)
  rs += __shfl_xor(rs, 16, 64);
  rs += __shfl_xor(rs, 32, 64);
  if (wn == 0 && lane < 16) rs2[kg][wm * 16 + lane] = rs;

  // kg=1 publishes its partial acc
  if (kg == 1) {
    int mre = wm * 16 + (lane >> 4) * 4;
    #pragma unroll
    for (int r = 0; r < 4; ++r) {
      comb[mre + r][n0]      = acc[0][r];
      comb[mre + r][n0 + 16] = acc[1][r];
      comb[mre + r][n0 + 32] = acc[2][r];
      comb[mre + r][n0 + 48] = acc[3][r];
    }
  }
  __syncthreads();
  if (t < 64) {
    float r = rs2[0][t] + rs2[1][t];
    float v = validf[i0 + t];
    scale_s[t] = (v > 0.f) ? 1.0f / fmaxf(r, 1e-30f) : 0.f;
  }
  __syncthreads();
  if (kg == 0) {
    int mre = wm * 16 + (lane >> 4) * 4;
    #pragma unroll
    for (int r = 0; r < 4; ++r) {
      float s = scale_s[mre + r];
      size_t base = (size_t)(i0 + mre + r) * A + colhalf * 128;
      out[base + n0]      = (acc[0][r] + comb[mre + r][n0]) * s;
      out[base + n0 + 16] = (acc[1][r] + comb[mre + r][n0 + 16]) * s;
      out[base + n0 + 32] = (acc[2][r] + comb[mre + r][n0 + 32]) * s;
      out[base + n0 + 48] = (acc[3][r] + comb[mre + r][n0 + 48]) * s;
    }
  }
}

extern "C" void kernel_launch(void* const* d_in, const int* in_sizes, int n_in,
                              void* d_out, int out_size, void* d_ws, size_t ws_size,
                              hipStream_t stream) {
  // inputs: 0 batch[S,F] 1 xywh[S,4] 2 OW 3 OH 4 actor_weights[S] 5 avg_pos[S,2]
  //         6 W_h[F,2] 7 b_h[2] 8 W_g[F,A] 9 b_g[A] 10 num_person
  const float* batch = (const float*)d_in[0];
  const float* xywh  = (const float*)d_in[1];
  const float* W_h   = (const float*)d_in[6];
  const float* b_h   = (const float*)d_in[7];
  const float* W_g   = (const float*)d_in[8];
  const float* b_g   = (const float*)d_in[9];
  int S = in_sizes[4];
  int F = in_sizes[0] / S;
  int A = in_sizes[9];

  float* out    = (float*)d_out;
  float* out_tw = out;                        // [S,A]
  float* out_hp = out + (size_t)S * A;        // [S,2]

  // workspace: tgt2 bf16 [S/32][A][32], WgT bf16 [A][F], hx/hy/validf, cxy
  uint16_t* tgt2 = (uint16_t*)d_ws;
  uint16_t* WgT  = tgt2 + (size_t)A * S;
  float* hxv = (float*)(WgT + (size_t)A * F);
  float* hyv = hxv + S;
  float* vfv = hyv + S;
  float2* cxyv = (float2*)(vfv + S);

  k_head<<<dim3((S + 3) / 4), 256, 0, stream>>>(batch, xywh, W_h, b_h,
                                                out_hp, hxv, hyv, vfv, cxyv, S, F);
  k_prep_w<<<dim3((A * F / 8 + 255) / 256), 256, 0, stream>>>(W_g, WgT, F, A);
  k_targets_mfma<<<dim3(S / 32), 256, 0, stream>>>(batch, WgT, b_g, tgt2, S, F, A);
  k_gather_v7<<<dim3(2, S / 64), 1024, 0, stream>>>(tgt2, cxyv, hxv, hyv, vfv,
                                                    out_tw, S, A);
}

// Round 8
// 155.729 us; speedup vs baseline: 6.1085x; 1.4318x over previous
//
#include <hip/hip_runtime.h>
#include <math.h>
#include <stdint.h>

typedef __attribute__((ext_vector_type(8))) short short8;
typedef __attribute__((ext_vector_type(4))) float f32x4;

__device__ __forceinline__ uint32_t cvt_pk_bf16(float lo, float hi) {
  uint32_t r;
  asm("v_cvt_pk_bf16_f32 %0, %1, %2" : "=v"(r) : "v"(lo), "v"(hi));
  return r;
}

// inverse-distance weight; invalid j has cx=cy=1e30 -> d2 overflows to inf
// -> rcp(inf)=0, so invalid columns contribute exactly 0.
__device__ __forceinline__ float wfun(float hx, float hy, float cx, float cy) {
  float dx = hx - cx, dy = hy - cy;
  float d = __builtin_amdgcn_sqrtf(fmaf(dx, dx, dy * dy));
  return __builtin_amdgcn_rcpf(d + 1e-4f);
}

// ---------------------------------------------------------------------------
// Kernel 1: hp = tanh(batch@W_h + b_h); hx,hy,validf,cxy per row. (verified)
__global__ __launch_bounds__(256) void k_head(
    const float* __restrict__ batch, const float* __restrict__ xywh,
    const float* __restrict__ W_h, const float* __restrict__ b_h,
    float* __restrict__ hp_out, float* __restrict__ hx, float* __restrict__ hy,
    float* __restrict__ validf, float2* __restrict__ cxy, int S, int F) {
  int wid = threadIdx.x >> 6;
  int lane = threadIdx.x & 63;
  int row = blockIdx.x * 4 + wid;
  if (row >= S) return;
  const float4* brow = (const float4*)(batch + (size_t)row * F);
  const float4* wh4 = (const float4*)W_h;  // W_h is [F,2] row-major
  int nf4 = F >> 2;
  float acc0 = 0.f, acc1 = 0.f;
  for (int k4 = lane; k4 < nf4; k4 += 64) {
    float4 b = brow[k4];
    float4 wa = wh4[2 * k4];
    float4 wb = wh4[2 * k4 + 1];
    acc0 += b.x * wa.x + b.y * wa.z + b.z * wb.x + b.w * wb.z;
    acc1 += b.x * wa.y + b.y * wa.w + b.z * wb.y + b.w * wb.w;
  }
  #pragma unroll
  for (int off = 32; off; off >>= 1) {
    acc0 += __shfl_xor(acc0, off, 64);
    acc1 += __shfl_xor(acc1, off, 64);
  }
  if (lane == 0) {
    float hp0 = tanhf(acc0 + b_h[0]);
    float hp1 = tanhf(acc1 + b_h[1]);
    float4 xy = ((const float4*)xywh)[row];
    hp_out[2 * row] = hp0;
    hp_out[2 * row + 1] = hp1;
    hx[row] = hp0 * xy.z * 4.0f + xy.x;  // SIGMA_X = 4
    hy[row] = hp1 * xy.w * 1.0f + xy.y;  // SIGMA_Y = 1
    bool v = (xy.x + xy.y + xy.z + xy.w >= 1e-8f);
    validf[row] = v ? 1.0f : 0.0f;
    cxy[row] = v ? make_float2(xy.x, xy.y) : make_float2(1e30f, 1e30f);
  }
}

// ---------------------------------------------------------------------------
// Kernel 1b: WgT[a][k] = bf16(Wg[k][a])  (verified)
__global__ __launch_bounds__(256) void k_prep_w(
    const float* __restrict__ Wg, uint16_t* __restrict__ WgT, int F, int A) {
  int idx = blockIdx.x * 256 + threadIdx.x;
  int a = idx % A;
  int k0 = (idx / A) * 8;
  if (k0 >= F) return;
  float f[8];
  #pragma unroll
  for (int e = 0; e < 8; ++e) f[e] = Wg[(size_t)(k0 + e) * A + a];
  uint4 v;
  v.x = cvt_pk_bf16(f[0], f[1]);
  v.y = cvt_pk_bf16(f[2], f[3]);
  v.z = cvt_pk_bf16(f[4], f[5]);
  v.w = cvt_pk_bf16(f[6], f[7]);
  *(uint4*)(WgT + (size_t)a * F + k0) = v;
}

// ---------------------------------------------------------------------------
// Kernel 2: targets via bf16 MFMA; tiled output tgt2[jb][a][jj]. (verified)
__global__ __launch_bounds__(256) void k_targets_mfma(
    const float* __restrict__ batch, const uint16_t* __restrict__ WgT,
    const float* __restrict__ bg, uint16_t* __restrict__ tgt2,
    int S, int F, int A) {
  int t = threadIdx.x;
  int lane = t & 63, wid = t >> 6;
  int wm = wid >> 1, wn = wid & 1;
  int i0 = blockIdx.x * 32;
  int row = i0 + wm * 16 + (lane & 15);
  int kch = lane >> 4;
  const float* ab = batch + (size_t)row * F + kch * 8;
  int ncol0 = wn * 128 + (lane & 15);
  const uint16_t* bb = WgT + (size_t)ncol0 * F + kch * 8;

  f32x4 acc[8] = {};
  float4 a0 = *(const float4*)(ab);
  float4 a1 = *(const float4*)(ab + 4);
  short8 bf[8];
  #pragma unroll
  for (int nf = 0; nf < 8; ++nf)
    bf[nf] = *(const short8*)(bb + (size_t)nf * 16 * F);

  for (int k0 = 0; k0 < F; k0 += 32) {
    int kn = (k0 + 32 < F) ? k0 + 32 : 0;  // wrap prefetch (harmless)
    float4 na0 = *(const float4*)(ab + kn);
    float4 na1 = *(const float4*)(ab + kn + 4);
    short8 nbf[8];
    #pragma unroll
    for (int nf = 0; nf < 8; ++nf)
      nbf[nf] = *(const short8*)(bb + kn + (size_t)nf * 16 * F);
    union { short8 s; uint32_t u[4]; } af;
    af.u[0] = cvt_pk_bf16(a0.x, a0.y);
    af.u[1] = cvt_pk_bf16(a0.z, a0.w);
    af.u[2] = cvt_pk_bf16(a1.x, a1.y);
    af.u[3] = cvt_pk_bf16(a1.z, a1.w);
    #pragma unroll
    for (int nf = 0; nf < 8; ++nf)
      acc[nf] = __builtin_amdgcn_mfma_f32_16x16x32_bf16(af.s, bf[nf], acc[nf], 0, 0, 0);
    a0 = na0; a1 = na1;
    #pragma unroll
    for (int nf = 0; nf < 8; ++nf) bf[nf] = nbf[nf];
  }

  int jb = blockIdx.x;
  int rloc = wm * 16 + (lane >> 4) * 4;   // row within tile, mult of 4
  #pragma unroll
  for (int nf = 0; nf < 8; ++nf) {
    int col = ncol0 + nf * 16;
    float b = bg[col];
    float o0 = fmaxf(acc[nf][0] + b, 0.f);
    float o1 = fmaxf(acc[nf][1] + b, 0.f);
    float o2 = fmaxf(acc[nf][2] + b, 0.f);
    float o3 = fmaxf(acc[nf][3] + b, 0.f);
    uint2 pk;
    pk.x = cvt_pk_bf16(o0, o1);
    pk.y = cvt_pk_bf16(o2, o3);
    *(uint2*)(tgt2 + ((size_t)jb * A + col) * 32 + rloc) = pk;
  }
}

// ---------------------------------------------------------------------------
// Kernel 3: out = rownorm(W) @ targets.  v7 math/epilogue verbatim; operands
// moved off the L1 request path: B-tiles (2 kg x 8 KB) and c-tiles staged in
// LDS via register double-buffer, one barrier/step. Per CU-step global load
// instrs drop 128 -> ~17. Padded Bt col stride (80 B) keeps ds_reads ~2-way.
__global__ __launch_bounds__(1024, 4) void k_gather_v8(
    const uint16_t* __restrict__ tgt2, const float2* __restrict__ cxy,
    const float* __restrict__ hx, const float* __restrict__ hy,
    const float* __restrict__ validf, float* __restrict__ out, int S, int A) {
  __shared__ uint16_t Bt[2][2][128][40];  // [dbuf][kg][col][40hw] 40 KB
  __shared__ float2  Ct[2][2][32];        // [dbuf][kg][jj]        1 KB
  __shared__ float comb[64][132];         // kg=1 partial acc      33.8 KB
  __shared__ float rs2[2][64];
  __shared__ float scale_s[64];

  int t = threadIdx.x;
  int lane = t & 63, wid = t >> 6;
  int kg = wid >> 3;                // 0..1
  int sub = wid & 7;
  int wm = sub >> 1, wn = sub & 1;  // 4M x 2N within K-group
  int colhalf = blockIdx.x;         // 0..1
  int i0 = blockIdx.y * 64;
  int mrow = i0 + wm * 16 + (lane & 15);
  int kch = lane >> 4;
  float hx_i = hx[mrow], hy_i = hy[mrow];
  int n0 = wn * 64 + (lane & 15);              // col within block (0..127)
  int nsteps = (S >> 1) / 32;                  // 128 tiles per K-group
  const size_t TSTRIDE = (size_t)A * 32;       // elements per j-tile

  // staging roles: every thread stages 16 B of B; threads 0..31 stage c.
  int skg = t >> 9;                 // == kg
  int su = t & 511;
  int scol = su >> 2;               // 0..127
  int skw = su & 3;                 // 0..3
  const uint16_t* gB0 = tgt2 + (size_t)(skg * nsteps) * TSTRIDE
                        + (size_t)colhalf * 128 * 32 + scol * 32 + skw * 8;
  const float2* gC0 = cxy + (size_t)(t >> 4) * (S >> 1) + (t & 15) * 2;

  f32x4 acc[4] = {};
  float rs = 0.f;

  // prologue: stage step 0
  {
    uint4 gb = *(const uint4*)(gB0);
    *(uint4*)&Bt[0][skg][scol][skw * 8] = gb;
    if (t < 32) {
      float4 gc = *(const float4*)(gC0);
      *(float4*)&Ct[0][t >> 4][(t & 15) * 2] = gc;
    }
  }
  __syncthreads();

  for (int ts = 0; ts < nsteps; ++ts) {
    int cur = ts & 1, nxt = cur ^ 1;
    int tn = (ts + 1 < nsteps) ? ts + 1 : 0;   // wrap stage (harmless)

    // issue next-step global loads into registers (latency hidden by compute)
    uint4 gb = *(const uint4*)(gB0 + (size_t)tn * TSTRIDE);
    float4 gc;
    if (t < 32) gc = *(const float4*)(gC0 + tn * 32);

    // c from LDS (broadcast within 16-lane groups)
    const float2* cp = &Ct[cur][kg][kch * 8];
    float4 c0 = *(const float4*)(cp);
    float4 c1 = *(const float4*)(cp + 2);
    float4 c2 = *(const float4*)(cp + 4);
    float4 c3 = *(const float4*)(cp + 6);

    // B frags from LDS
    short8 b0 = *(const short8*)&Bt[cur][kg][n0][kch * 8];
    short8 b1 = *(const short8*)&Bt[cur][kg][n0 + 16][kch * 8];
    short8 b2 = *(const short8*)&Bt[cur][kg][n0 + 32][kch * 8];
    short8 b3 = *(const short8*)&Bt[cur][kg][n0 + 48][kch * 8];

    // 8 w's for this lane's A fragment (row=lane&15, k=(lane>>4)*8+e)
    float w0 = wfun(hx_i, hy_i, c0.x, c0.y);
    float w1 = wfun(hx_i, hy_i, c0.z, c0.w);
    float w2 = wfun(hx_i, hy_i, c1.x, c1.y);
    float w3 = wfun(hx_i, hy_i, c1.z, c1.w);
    float w4 = wfun(hx_i, hy_i, c2.x, c2.y);
    float w5 = wfun(hx_i, hy_i, c2.z, c2.w);
    float w6 = wfun(hx_i, hy_i, c3.x, c3.y);
    float w7 = wfun(hx_i, hy_i, c3.z, c3.w);
    rs += ((w0 + w1) + (w2 + w3)) + ((w4 + w5) + (w6 + w7));
    union { short8 s; uint32_t u[4]; } af;
    af.u[0] = cvt_pk_bf16(w0, w1);
    af.u[1] = cvt_pk_bf16(w2, w3);
    af.u[2] = cvt_pk_bf16(w4, w5);
    af.u[3] = cvt_pk_bf16(w6, w7);

    acc[0] = __builtin_amdgcn_mfma_f32_16x16x32_bf16(af.s, b0, acc[0], 0, 0, 0);
    acc[1] = __builtin_amdgcn_mfma_f32_16x16x32_bf16(af.s, b1, acc[1], 0, 0, 0);
    acc[2] = __builtin_amdgcn_mfma_f32_16x16x32_bf16(af.s, b2, acc[2], 0, 0, 0);
    acc[3] = __builtin_amdgcn_mfma_f32_16x16x32_bf16(af.s, b3, acc[3], 0, 0, 0);

    // write staged data to the other buffer (compiler inserts vmcnt waits)
    *(uint4*)&Bt[nxt][skg][scol][skw * 8] = gb;
    if (t < 32) *(float4*)&Ct[nxt][t >> 4][(t & 15) * 2] = gc;
    __syncthreads();
  }

  // per-kg row sums: combine the 4 kch groups (wn waves hold identical sums)
  rs += __shfl_xor(rs, 16, 64);
  rs += __shfl_xor(rs, 32, 64);
  if (wn == 0 && lane < 16) rs2[kg][wm * 16 + lane] = rs;

  // kg=1 publishes its partial acc
  if (kg == 1) {
    int mre = wm * 16 + (lane >> 4) * 4;
    #pragma unroll
    for (int r = 0; r < 4; ++r) {
      comb[mre + r][n0]      = acc[0][r];
      comb[mre + r][n0 + 16] = acc[1][r];
      comb[mre + r][n0 + 32] = acc[2][r];
      comb[mre + r][n0 + 48] = acc[3][r];
    }
  }
  __syncthreads();
  if (t < 64) {
    float r = rs2[0][t] + rs2[1][t];
    float v = validf[i0 + t];
    scale_s[t] = (v > 0.f) ? 1.0f / fmaxf(r, 1e-30f) : 0.f;
  }
  __syncthreads();
  if (kg == 0) {
    int mre = wm * 16 + (lane >> 4) * 4;
    #pragma unroll
    for (int r = 0; r < 4; ++r) {
      float s = scale_s[mre + r];
      size_t base = (size_t)(i0 + mre + r) * A + colhalf * 128;
      out[base + n0]      = (acc[0][r] + comb[mre + r][n0]) * s;
      out[base + n0 + 16] = (acc[1][r] + comb[mre + r][n0 + 16]) * s;
      out[base + n0 + 32] = (acc[2][r] + comb[mre + r][n0 + 32]) * s;
      out[base + n0 + 48] = (acc[3][r] + comb[mre + r][n0 + 48]) * s;
    }
  }
}

extern "C" void kernel_launch(void* const* d_in, const int* in_sizes, int n_in,
                              void* d_out, int out_size, void* d_ws, size_t ws_size,
                              hipStream_t stream) {
  // inputs: 0 batch[S,F] 1 xywh[S,4] 2 OW 3 OH 4 actor_weights[S] 5 avg_pos[S,2]
  //         6 W_h[F,2] 7 b_h[2] 8 W_g[F,A] 9 b_g[A] 10 num_person
  const float* batch = (const float*)d_in[0];
  const float* xywh  = (const float*)d_in[1];
  const float* W_h   = (const float*)d_in[6];
  const float* b_h   = (const float*)d_in[7];
  const float* W_g   = (const float*)d_in[8];
  const float* b_g   = (const float*)d_in[9];
  int S = in_sizes[4];
  int F = in_sizes[0] / S;
  int A = in_sizes[9];

  float* out    = (float*)d_out;
  float* out_tw = out;                        // [S,A]
  float* out_hp = out + (size_t)S * A;        // [S,2]

  // workspace: tgt2 bf16 [S/32][A][32], WgT bf16 [A][F], hx/hy/validf, cxy
  uint16_t* tgt2 = (uint16_t*)d_ws;
  uint16_t* WgT  = tgt2 + (size_t)A * S;
  float* hxv = (float*)(WgT + (size_t)A * F);
  float* hyv = hxv + S;
  float* vfv = hyv + S;
  float2* cxyv = (float2*)(vfv + S);

  k_head<<<dim3((S + 3) / 4), 256, 0, stream>>>(batch, xywh, W_h, b_h,
                                                out_hp, hxv, hyv, vfv, cxyv, S, F);
  k_prep_w<<<dim3((A * F / 8 + 255) / 256), 256, 0, stream>>>(W_g, WgT, F, A);
  k_targets_mfma<<<dim3(S / 32), 256, 0, stream>>>(batch, WgT, b_g, tgt2, S, F, A);
  k_gather_v8<<<dim3(2, S / 64), 1024, 0, stream>>>(tgt2, cxyv, hxv, hyv, vfv,
                                                    out_tw, S, A);
}